// Round 6
// baseline (171.597 us; speedup 1.0000x reference)
//
#include <hip/hip_runtime.h>
#include <math.h>

#define BB 32
#define LL 512
#define DD 32
#define KK 6
#define OO 192
#define DM 512

typedef __fp16 h2 __attribute__((ext_vector_type(2)));
union F2H { float f; h2 h; };
__device__ __forceinline__ float asF(h2 h) { F2H u; u.h = h; return u.f; }
__device__ __forceinline__ h2 asH(float f) { F2H u; u.f = f; return u.h; }

typedef short bf16x8 __attribute__((ext_vector_type(8)));
typedef float f4 __attribute__((ext_vector_type(4)));
union U16x8 { uint4 u; bf16x8 h; };

__device__ __forceinline__ unsigned short f2bf(float x) {   // RNE f32->bf16
  unsigned int u = __float_as_uint(x);
  u = (u + 0x7FFF + ((u >> 16) & 1)) >> 16;
  return (unsigned short)u;
}

#define MOVDPP(x, ctrl) \
  __int_as_float(__builtin_amdgcn_mov_dpp(__float_as_int(x), ctrl, 0xf, 0xf, true))

// LDS layout (float slots) for fused kernel (d-quad blocks)
#define XDSTR 26                 // 24 cols + 2 pad (even -> float2-aligned writes)
#define XD0   0                  // raw x_date rows: [512][26]  (13312)
#define XV0   13312              // raw x rows:      [512][5]   (2560)
#define MEDO  15872              // 28 (24 map cols + 4 x cols)
#define STDO  15900              // 28
#define SAO   15928              // 24
#define SCO   15952              // 24
#define PK    0                  // packed attn rows overlay XD: [4][512][4] (8192)
#define LDSF  15976              // 63.9 KB (2 blocks/CU capacity)

// ---------------------------------------------------------------------------
// In-register bitonic sort of 512 floats across one wave (8 elems/lane).
// ---------------------------------------------------------------------------
__device__ __forceinline__ void sort512(float v[8], int lane) {
  #pragma unroll
  for (int k = 2; k <= 512; k <<= 1) {
    #pragma unroll
    for (int j = k >> 1; j > 0; j >>= 1) {
      if (j >= 8) {
        int jj = j >> 3;
        bool lower = (lane & jj) == 0;
        bool asc = ((lane << 3) & k) == 0;
        bool keepmin = (asc == lower);
        #pragma unroll
        for (int r = 0; r < 8; ++r) {
          float o;
          if (jj == 1)      o = MOVDPP(v[r], 0xB1);   // quad_perm [1,0,3,2]
          else if (jj == 2) o = MOVDPP(v[r], 0x4E);   // quad_perm [2,3,0,1]
          else if (jj == 8) o = MOVDPP(v[r], 0x128);  // row_ror:8 == xor8
          else              o = __shfl_xor(v[r], jj);
          v[r] = keepmin ? fminf(v[r], o) : fmaxf(v[r], o);
        }
      } else {
        #pragma unroll
        for (int r = 0; r < 8; ++r) {
          if ((r & j) == 0) {
            int r2 = r | j;
            bool asc = (((lane << 3) | r) & k) == 0;
            float a = v[r], b = v[r2];
            float lo = fminf(a, b), hi = fmaxf(a, b);
            v[r]  = asc ? lo : hi;
            v[r2] = asc ? hi : lo;
          }
        }
      }
    }
  }
}

// ---------------------------------------------------------------------------
// K1 fused: blocks 0..255 = (b, d-quad). Staging of x_date/x is COALESCED
// (the quad's 24 floats per row are contiguous & 16B-aligned). 28 sorts per
// block = 7 serial per wave. Attention is wave-per-d (no cross-wave reduce).
// Blocks 256..319: w1 -> w1t bf16 transpose for the tail MFMA.
// ---------------------------------------------------------------------------
__global__ __launch_bounds__(256) void fused_kernel(
    const float* __restrict__ x, const float* __restrict__ x_date,
    const float* __restrict__ y_date, const float* __restrict__ w1,
    float* __restrict__ V, float* __restrict__ ymean,
    float* __restrict__ bnp, unsigned short* __restrict__ errb,
    unsigned short* __restrict__ w1t) {
  __shared__ float lds[LDSF];
  int orig = blockIdx.x;
  int tid = threadIdx.x, lane = tid & 63, wv = tid >> 6;

  if (orig >= 256) {
    // ---- w1 -> w1t bf16, 64x64 tile (independent of main path) ----
    float* tw = lds;                           // 64*68 = 4352 floats
    int id = orig - 256;                       // 0..63
    int l0 = (id & 7) * 64, m0 = (id >> 3) * 64;
    #pragma unroll
    for (int it = 0; it < 4; ++it) {           // 64 l-rows x 16 float4
      int f = tid + it * 256;
      int row = f >> 4, c4 = f & 15;
      float4 v = ((const float4*)(w1 + (size_t)(l0 + row) * DM + m0))[c4];
      float* p = &tw[row * 68 + c4 * 4];
      p[0] = v.x; p[1] = v.y; p[2] = v.z; p[3] = v.w;
    }
    __syncthreads();
    unsigned int* w1t32 = (unsigned int*)w1t;
    #pragma unroll
    for (int it = 0; it < 8; ++it) {           // 64 m-rows x 32 uints
      int f = tid + it * 256;
      int mr = f >> 5, c = f & 31;
      float a = tw[(c * 2 + 0) * 68 + mr];
      float b = tw[(c * 2 + 1) * 68 + mr];
      unsigned int u = (unsigned int)f2bf(a) | ((unsigned int)f2bf(b) << 16);
      w1t32[(size_t)(m0 + mr) * (DM / 2) + (l0 >> 1) + c] = u;
    }
    return;
  }

  // XCD-aware swizzle: all 8 d-quads + 4 b's colocate per XCD for L2 reuse.
  int xcd = orig & 7, idx = orig >> 3;         // idx 0..31
  int b = (xcd << 2) | (idx >> 3);
  int d0 = (idx & 7) << 2;                     // quad base d

  // ---- coalesced staging: x_date quad-rows (6 float4) + x rows (1 float4) --
  const float* xs = x_date + (size_t)b * LL * 192 + d0 * 6;
  #pragma unroll
  for (int it = 0; it < 12; ++it) {            // 512 rows x 6 float4
    int f = tid + it * 256;
    int row = f / 6, c4 = f % 6;
    float4 v = ((const float4*)(xs + (size_t)row * 192))[c4];
    float* p = &lds[XD0 + row * XDSTR + c4 * 4];
    *(float2*)p       = make_float2(v.x, v.y);     // base even -> 8B aligned
    *(float2*)(p + 2) = make_float2(v.z, v.w);
  }
  #pragma unroll
  for (int it = 0; it < 2; ++it) {             // 512 rows x 1 float4 (4 d's)
    int row = tid + it * 256;
    float4 v = *(const float4*)(x + ((size_t)(b * LL + row)) * DD + d0);
    float* p = &lds[XV0 + row * 5];
    p[0] = v.x; p[1] = v.y; p[2] = v.z; p[3] = v.w;
  }

  // ---- prefetch this wave's y_date column (d = d0+wv) into regs ----
  float2 yr[3][3];
  {
    int dme = d0 + wv;
    #pragma unroll
    for (int j = 0; j < 3; ++j) {
      const float2* yp = (const float2*)(
          y_date + (((size_t)b * OO + (lane + 64 * j)) * DD + dme) * KK);
      yr[j][0] = yp[0]; yr[j][1] = yp[1]; yr[j][2] = yp[2];
    }
  }
  __syncthreads();

  // ---- 28 sorts: 7 passes x 4 waves.  s<24: x_date col, s>=24: x col ----
  for (int p = 0; p < 7; ++p) {
    int s = p * 4 + wv;
    float v[8];
    if (s < 24) {
      #pragma unroll
      for (int r = 0; r < 8; ++r) v[r] = lds[XD0 + (lane * 8 + r) * XDSTR + s];
    } else {
      #pragma unroll
      for (int r = 0; r < 8; ++r) v[r] = lds[XV0 + (lane * 8 + r) * 5 + (s - 24)];
    }
    sort512(v, lane);
    float e127 = __shfl(v[7], 15);
    float e128 = __shfl(v[0], 16);
    float e255 = __shfl(v[7], 31);
    float e383 = __shfl(v[7], 47);
    float e384 = __shfl(v[0], 48);
    if (lane == 0) {
      float q25 = e127 + 0.75f * (e128 - e127);   // 0.25*(n-1)=127.75
      float q75 = e383 + 0.25f * (e384 - e383);   // 0.75*(n-1)=383.25
      lds[MEDO + s] = e255;                       // torch lower-median
      lds[STDO + s] = q75 - q25 + 1e-6f;
    }
  }
  __syncthreads();

  if (tid < 24) {
    int dloc = tid / 6;
    float a = lds[STDO + 24 + dloc] / lds[STDO + tid];
    lds[SAO + tid] = a;
    lds[SCO + tid] = lds[MEDO + 24 + dloc] - lds[MEDO + tid] * a;
  }
  __syncthreads();

  const float PSC = 0.58912435f;   // (1/sqrt(6)) * log2(e)

  // ---- affine map + err (bf16 to global) + packed attn rows in regs ----
  float4 packed[2][4];
  #pragma unroll
  for (int dl = 0; dl < 4; ++dl) {
    int cb = dl * 6;
    float a0 = lds[SAO+cb+0], a1 = lds[SAO+cb+1], a2 = lds[SAO+cb+2];
    float a3 = lds[SAO+cb+3], a4 = lds[SAO+cb+4], a5 = lds[SAO+cb+5];
    float c0 = lds[SCO+cb+0], c1 = lds[SCO+cb+1], c2 = lds[SCO+cb+2];
    float c3 = lds[SCO+cb+3], c4 = lds[SCO+cb+4], c5 = lds[SCO+cb+5];
    #pragma unroll
    for (int it = 0; it < 2; ++it) {
      int l = tid + it * 256;
      const float* row = &lds[XD0 + l * XDSTR + cb];
      float m0 = a0 * row[0] + c0;
      float m1 = a1 * row[1] + c1;
      float m2 = a2 * row[2] + c2;
      float m3 = a3 * row[3] + c3;
      float m4 = a4 * row[4] + c4;
      float m5 = a5 * row[5] + c5;
      float xvv = lds[XV0 + l * 5 + dl];
      errb[(size_t)((b << 5) | (d0 + dl)) * LL + l] =
          f2bf(xvv - (m0 + m1 + m2 + m3 + m4 + m5) * (1.0f / 6.0f));
      packed[it][dl].x = asF(__builtin_amdgcn_cvt_pkrtz(m0 * PSC, m1 * PSC));
      packed[it][dl].y = asF(__builtin_amdgcn_cvt_pkrtz(m2 * PSC, m3 * PSC));
      packed[it][dl].z = asF(__builtin_amdgcn_cvt_pkrtz(m4 * PSC, m5 * PSC));
      packed[it][dl].w = asF(__builtin_amdgcn_cvt_pkrtz(xvv, 0.0f));
    }
  }
  __syncthreads();   // all XD/XV reads done; safe to overlay with PK

  #pragma unroll
  for (int it = 0; it < 2; ++it) {
    int l = tid + it * 256;
    #pragma unroll
    for (int dl = 0; dl < 4; ++dl)
      *(float4*)&lds[PK + dl * 2048 + l * 4] = packed[it][dl];
  }
  __syncthreads();

  // ---- attention, wave-per-d: full 512 l x 192 o for d = d0+wv ----
  {
    int dme = d0 + wv;
    float askw[6], cskw[6];
    #pragma unroll
    for (int k = 0; k < 6; ++k) {
      askw[k] = lds[SAO + wv * 6 + k];
      cskw[k] = lds[SCO + wv * 6 + k];
    }
    h2 yk[3][3];
    #pragma unroll
    for (int j = 0; j < 3; ++j) {
      float q0 = askw[0] * yr[j][0].x + cskw[0];
      float q1 = askw[1] * yr[j][0].y + cskw[1];
      float q2 = askw[2] * yr[j][1].x + cskw[2];
      float q3 = askw[3] * yr[j][1].y + cskw[3];
      float q4 = askw[4] * yr[j][2].x + cskw[4];
      float q5 = askw[5] * yr[j][2].y + cskw[5];
      ymean[(size_t)((b << 5) | dme) * OO + (lane + 64 * j)] =
          (q0 + q1 + q2 + q3 + q4 + q5) * (1.0f / 6.0f);
      yk[j][0] = __builtin_amdgcn_cvt_pkrtz(q0, q1);
      yk[j][1] = __builtin_amdgcn_cvt_pkrtz(q2, q3);
      yk[j][2] = __builtin_amdgcn_cvt_pkrtz(q4, q5);
    }

    float den[3] = {0.f, 0.f, 0.f}, num[3] = {0.f, 0.f, 0.f};
    const float* pk = &lds[PK + wv * 2048];
    #pragma unroll 4
    for (int l = 0; l < LL; ++l) {
      float4 rw = *(const float4*)&pk[l * 4];   // wave-uniform broadcast
      h2 x01 = asH(rw.x), x23 = asH(rw.y), x45 = asH(rw.z);
      float xf = (float)(asH(rw.w).x);
      #pragma unroll
      for (int j = 0; j < 3; ++j) {
        float sc = __builtin_amdgcn_fdot2(x01, yk[j][0], 0.0f, false);
        sc = __builtin_amdgcn_fdot2(x23, yk[j][1], sc, false);
        sc = __builtin_amdgcn_fdot2(x45, yk[j][2], sc, false);
        float e = exp2f(sc);     // scale folded into x-side pack
        den[j] += e;
        num[j] += e * xf;
      }
    }

    float s1 = 0.f, s2 = 0.f;
    #pragma unroll
    for (int j = 0; j < 3; ++j) {
      float vv = num[j] / den[j];
      V[(size_t)((b << 5) | dme) * OO + (lane + 64 * j)] = vv;
      s1 += vv; s2 += vv * vv;
    }
    #pragma unroll
    for (int off = 32; off > 0; off >>= 1) {
      s1 += __shfl_down(s1, off);
      s2 += __shfl_down(s2, off);
    }
    if (lane == 0) {
      bnp[(dme << 5) | b]          = s1;   // no atomics: per-(d,b) partials
      bnp[1024 + ((dme << 5) | b)] = s2;
    }
  }
}

// ---------------------------------------------------------------------------
// K2 tail: 256 blocks = (b, o-eighth of 24). Each block REDUNDANTLY computes
// its b's 32-row gating GEMM via MFMA (w1t is L2-resident), bn constants from
// bnp partials, then the final fusion for its 24 o's.
// ---------------------------------------------------------------------------
__global__ __launch_bounds__(256) void tail_kernel(
    const unsigned short* __restrict__ errb, const unsigned short* __restrict__ w1t,
    const float* __restrict__ b1, const float* __restrict__ w2,
    const float* __restrict__ b2, const float* __restrict__ V,
    const float* __restrict__ ymean, const float* __restrict__ bnp,
    const float* __restrict__ gamma, const float* __restrict__ beta,
    float* __restrict__ out) {
  __shared__ float vsh[32 * 28], ysh[32 * 28];
  __shared__ float part[4][32];
  __shared__ float gsh[32], ssh[32], osh[32];
  int g = blockIdx.x, tid = threadIdx.x;
  int b = g >> 3, o0 = (g & 7) * 24;
  int lane = tid & 63, wv = tid >> 6;
  int m16 = lane & 15, quad = lane >> 4;
  int mw = wv * 128;
  int r0 = b * 32;

  // ---- stage V/ymean for (b, o-slice): 32 d x 6 float4 ----
  if (tid < 192) {
    int dd = tid / 6, c4 = tid % 6;
    size_t goff = (size_t)(b * DD + dd) * OO + o0;
    float4 v = ((const float4*)(V + goff))[c4];
    float4 y = ((const float4*)(ymean + goff))[c4];
    *(float4*)&vsh[dd * 28 + c4 * 4] = v;
    *(float4*)&ysh[dd * 28 + c4 * 4] = y;
  }

  // ---- gating GEMM: rows r0..r0+31 x all 512 m (wave: 128 m) ----
  float b1v[8], w2d[8];
  #pragma unroll
  for (int ct = 0; ct < 8; ++ct) {
    int m = mw + ct * 16 + m16;
    b1v[ct] = b1[m];
    float2 w2p = ((const float2*)w2)[m];
    w2d[ct] = w2p.x - w2p.y;
  }

  f4 acc[2][8];
  #pragma unroll
  for (int rt = 0; rt < 2; ++rt)
    #pragma unroll
    for (int ct = 0; ct < 8; ++ct)
      acc[rt][ct] = (f4){0.f, 0.f, 0.f, 0.f};

  const unsigned short* ea = errb + (size_t)(r0 + m16) * DM + quad * 8;
  const unsigned short* eb = ea + 16 * DM;
  const unsigned short* wb = w1t + (size_t)(mw + m16) * DM + quad * 8;

  for (int ks = 0; ks < DM; ks += 32) {
    U16x8 ua0, ua1;
    ua0.u = *(const uint4*)(ea + ks);
    ua1.u = *(const uint4*)(eb + ks);
    #pragma unroll
    for (int ct = 0; ct < 8; ++ct) {
      U16x8 ub;
      ub.u = *(const uint4*)(wb + (size_t)ct * 16 * DM + ks);
      acc[0][ct] = __builtin_amdgcn_mfma_f32_16x16x32_bf16(ua0.h, ub.h, acc[0][ct], 0, 0, 0);
      acc[1][ct] = __builtin_amdgcn_mfma_f32_16x16x32_bf16(ua1.h, ub.h, acc[1][ct], 0, 0, 0);
    }
  }

  #pragma unroll
  for (int rt = 0; rt < 2; ++rt) {
    float rsum[4] = {0.f, 0.f, 0.f, 0.f};
    #pragma unroll
    for (int ct = 0; ct < 8; ++ct) {
      #pragma unroll
      for (int r = 0; r < 4; ++r) {
        float h = acc[rt][ct][r] + b1v[ct];
        float gg = 0.5f * h * (1.0f + erff(h * 0.70710678f));
        rsum[r] += gg * w2d[ct];
      }
    }
    #pragma unroll
    for (int r = 0; r < 4; ++r) {
      rsum[r] += __shfl_xor(rsum[r], 1);
      rsum[r] += __shfl_xor(rsum[r], 2);
      rsum[r] += __shfl_xor(rsum[r], 4);
      rsum[r] += __shfl_xor(rsum[r], 8);
    }
    if (m16 == 0) {
      #pragma unroll
      for (int r = 0; r < 4; ++r)
        part[wv][rt * 16 + quad * 4 + r] = rsum[r];
    }
  }
  __syncthreads();

  if (tid < 32) {
    float ld = b2[0] - b2[1]
             + part[0][tid] + part[1][tid] + part[2][tid] + part[3][tid];
    gsh[tid] = 1.0f / (1.0f + expf(-ld));      // gate w0 for (b, d=tid)
    float S = 0.f, S2 = 0.f;
    const float* pd = bnp + (tid << 5);
    #pragma unroll 8
    for (int bb = 0; bb < 32; ++bb) { S += pd[bb]; S2 += pd[1024 + bb]; }
    const float inv = 1.0f / (BB * OO);
    float mu = S * inv;
    float var = S2 * inv - mu * mu;
    float gg = gamma[tid] * rsqrtf(var + 1e-5f);
    ssh[tid] = gg;
    osh[tid] = beta[tid] - mu * gg;
  }
  __syncthreads();

  // ---- final fusion: 24 o x 8 float4 (32 d), coalesced out writes ----
  if (tid < 192) {
    int op = tid >> 3, c4 = tid & 7;
    float4 r;
    #pragma unroll
    for (int j = 0; j < 4; ++j) {
      int dd = c4 * 4 + j;
      float v  = vsh[dd * 28 + op];
      float ym = ysh[dd * 28 + op];
      float gg = gsh[dd];
      float y  = v * ssh[dd] + osh[dd];
      ((float*)&r)[j] = ym * gg + y * (1.0f - gg);
    }
    ((float4*)(out + (size_t)(b * OO + o0 + op) * DD))[c4] = r;
  }
}

// ---------------------------------------------------------------------------
extern "C" void kernel_launch(void* const* d_in, const int* in_sizes, int n_in,
                              void* d_out, int out_size, void* d_ws, size_t ws_size,
                              hipStream_t stream) {
  const float* x      = (const float*)d_in[0];
  const float* x_date = (const float*)d_in[1];
  const float* y_date = (const float*)d_in[2];
  const float* w1     = (const float*)d_in[3];
  const float* b1     = (const float*)d_in[4];
  const float* w2     = (const float*)d_in[5];
  const float* b2     = (const float*)d_in[6];
  const float* gamma  = (const float*)d_in[7];
  const float* beta   = (const float*)d_in[8];
  float* out = (float*)d_out;

  float* ws    = (float*)d_ws;
  float* V     = ws;                             // [0, 196608)   (B,D,O)
  float* ymean = ws + 196608;                    // [196608, 393216)
  float* bnp   = ws + 393216;                    // [393216, 395264)
  unsigned short* errb = (unsigned short*)(ws + 395264);   // [395264, 657408) 1024x512 bf16
  unsigned short* w1t  = (unsigned short*)(ws + 657408);   // [657408, 788480) 512x512 bf16 (m,l)

  fused_kernel<<<320, 256, 0, stream>>>(x, x_date, y_date, w1,
                                        V, ymean, bnp, errb, w1t);
  tail_kernel<<<256, 256, 0, stream>>>(errb, w1t, b1, w2, b2, V, ymean,
                                       bnp, gamma, beta, out);
}

// Round 7
// 160.218 us; speedup vs baseline: 1.0710x; 1.0710x over previous
//
#include <hip/hip_runtime.h>
#include <math.h>

#define BB 32
#define LL 512
#define DD 32
#define KK 6
#define OO 192
#define DM 512

typedef __fp16 h2 __attribute__((ext_vector_type(2)));
union F2H { float f; h2 h; };
__device__ __forceinline__ float asF(h2 h) { F2H u; u.h = h; return u.f; }
__device__ __forceinline__ h2 asH(float f) { F2H u; u.f = f; return u.h; }

typedef short bf16x8 __attribute__((ext_vector_type(8)));
typedef float f4 __attribute__((ext_vector_type(4)));
union U16x8 { uint4 u; bf16x8 h; };

__device__ __forceinline__ unsigned short f2bf(float x) {   // RNE f32->bf16
  unsigned int u = __float_as_uint(x);
  u = (u + 0x7FFF + ((u >> 16) & 1)) >> 16;
  return (unsigned short)u;
}

#define MOVDPP(x, ctrl) \
  __int_as_float(__builtin_amdgcn_mov_dpp(__float_as_int(x), ctrl, 0xf, 0xf, true))

// LDS layout (float slots), d-pair blocks, COLUMN-MAJOR x/x_date storage.
// CSTR2=524: 16B-aligned columns (sort gather = R0's conflict-free b128),
// and 4*524 % 32 == 16 -> transpose-writes ~2-way (free).
#define CSTR2 524
#define XD0   0                  // 12 cols x 524           (6288)
#define XV0   6288               // 2 cols x 524            (1048) -> 7336
#define MEDO  7336               // 14
#define STDO  7350               // 14
#define SAO   7364               // 12
#define SCO   7376               // 12
#define BNR   7388               // 16 bn wave partials
#define PK    0                  // overlay: packed rows [2][512][4] (4096)
#define DENB  4200               // overlay: [4 wv][192]     (768)
#define NUMB  4968               // overlay: [4 wv][192]     (768) -> 5736 < 6288
#define LDSF  7404               // 29.6 KB

// ---------------------------------------------------------------------------
// In-register bitonic sort of 512 floats across one wave (8 elems/lane).
// ---------------------------------------------------------------------------
__device__ __forceinline__ void sort512(float v[8], int lane) {
  #pragma unroll
  for (int k = 2; k <= 512; k <<= 1) {
    #pragma unroll
    for (int j = k >> 1; j > 0; j >>= 1) {
      if (j >= 8) {
        int jj = j >> 3;
        bool lower = (lane & jj) == 0;
        bool asc = ((lane << 3) & k) == 0;
        bool keepmin = (asc == lower);
        #pragma unroll
        for (int r = 0; r < 8; ++r) {
          float o;
          if (jj == 1)      o = MOVDPP(v[r], 0xB1);   // quad_perm [1,0,3,2]
          else if (jj == 2) o = MOVDPP(v[r], 0x4E);   // quad_perm [2,3,0,1]
          else if (jj == 8) o = MOVDPP(v[r], 0x128);  // row_ror:8 == xor8
          else              o = __shfl_xor(v[r], jj);
          v[r] = keepmin ? fminf(v[r], o) : fmaxf(v[r], o);
        }
      } else {
        #pragma unroll
        for (int r = 0; r < 8; ++r) {
          if ((r & j) == 0) {
            int r2 = r | j;
            bool asc = (((lane << 3) | r) & k) == 0;
            float a = v[r], b = v[r2];
            float lo = fminf(a, b), hi = fmaxf(a, b);
            v[r]  = asc ? lo : hi;
            v[r2] = asc ? hi : lo;
          }
        }
      }
    }
  }
}

// ---------------------------------------------------------------------------
// K1 fused: blocks 0..511 = (b, d-pair). Coalesced global reads, column-major
// LDS store (transpose-on-write). 14 sorts over 4 waves. Attention: wave =
// (d of pair, l-half), LDS den/num combine. Blocks 512..575: w1 -> w1t bf16.
// ---------------------------------------------------------------------------
__global__ __launch_bounds__(256) void fused_kernel(
    const float* __restrict__ x, const float* __restrict__ x_date,
    const float* __restrict__ y_date, const float* __restrict__ w1,
    float* __restrict__ V, float* __restrict__ ymean,
    float* __restrict__ bnp, unsigned short* __restrict__ errb,
    unsigned short* __restrict__ w1t) {
  __shared__ float lds[LDSF];
  int orig = blockIdx.x;
  int tid = threadIdx.x, lane = tid & 63, wv = tid >> 6;

  if (orig >= 512) {
    // ---- w1 -> w1t bf16, 64x64 tile (independent of main path) ----
    float* tw = lds;                           // 64*68 = 4352 floats
    int id = orig - 512;                       // 0..63
    int l0 = (id & 7) * 64, m0 = (id >> 3) * 64;
    #pragma unroll
    for (int it = 0; it < 4; ++it) {           // 64 l-rows x 16 float4
      int f = tid + it * 256;
      int row = f >> 4, c4 = f & 15;
      float4 v = ((const float4*)(w1 + (size_t)(l0 + row) * DM + m0))[c4];
      float* p = &tw[row * 68 + c4 * 4];
      p[0] = v.x; p[1] = v.y; p[2] = v.z; p[3] = v.w;
    }
    __syncthreads();
    unsigned int* w1t32 = (unsigned int*)w1t;
    #pragma unroll
    for (int it = 0; it < 8; ++it) {           // 64 m-rows x 32 uints
      int f = tid + it * 256;
      int mr = f >> 5, c = f & 31;
      float a = tw[(c * 2 + 0) * 68 + mr];
      float b = tw[(c * 2 + 1) * 68 + mr];
      unsigned int u = (unsigned int)f2bf(a) | ((unsigned int)f2bf(b) << 16);
      w1t32[(size_t)(m0 + mr) * (DM / 2) + (l0 >> 1) + c] = u;
    }
    return;
  }

  // XCD-aware swizzle: 64 blocks per XCD = 4 b's x 16 d-pairs.
  int xcd = orig & 7, idx = orig >> 3;         // idx 0..63
  int b = (xcd << 2) | (idx >> 4);
  int d0 = (idx & 15) << 1;                    // pair base d

  // ---- coalesced read + transpose-on-write: x_date rows (3 float4) ----
  const float* xs = x_date + (size_t)b * LL * 192 + d0 * 6;
  #pragma unroll
  for (int it = 0; it < 6; ++it) {             // 512 rows x 3 float4
    int f = tid + it * 256;
    int row = f / 3, c4 = f % 3;
    float4 v = ((const float4*)(xs + (size_t)row * 192))[c4];
    int col = c4 * 4;
    lds[XD0 + (col + 0) * CSTR2 + row] = v.x;
    lds[XD0 + (col + 1) * CSTR2 + row] = v.y;
    lds[XD0 + (col + 2) * CSTR2 + row] = v.z;
    lds[XD0 + (col + 3) * CSTR2 + row] = v.w;
  }
  #pragma unroll
  for (int it = 0; it < 2; ++it) {             // 512 rows x float2 (2 d's)
    int row = tid + it * 256;
    float2 v = *(const float2*)(x + (size_t)(b * LL + row) * DD + d0);
    lds[XV0 + row]         = v.x;
    lds[XV0 + CSTR2 + row] = v.y;
  }

  // ---- prefetch this wave's y_date column (d = d0 + (wv>>1)) ----
  int dl = wv >> 1, half = wv & 1;
  int dme = d0 + dl;
  float2 yr[3][3];
  #pragma unroll
  for (int j = 0; j < 3; ++j) {
    const float2* yp = (const float2*)(
        y_date + (((size_t)b * OO + (lane + 64 * j)) * DD + dme) * KK);
    yr[j][0] = yp[0]; yr[j][1] = yp[1]; yr[j][2] = yp[2];
  }
  __syncthreads();

  // ---- 14 sorts: 4 rounds x 4 waves.  s<12: x_date col, s>=12: x col ----
  for (int p = 0; p < 4; ++p) {
    int s = p * 4 + wv;
    if (s < 14) {
      const float4* colp = (s < 12)
          ? (const float4*)&lds[XD0 + s * CSTR2 + lane * 8]
          : (const float4*)&lds[XV0 + (s - 12) * CSTR2 + lane * 8];
      float v[8];
      float4 c0 = colp[0], c1 = colp[1];
      v[0]=c0.x; v[1]=c0.y; v[2]=c0.z; v[3]=c0.w;
      v[4]=c1.x; v[5]=c1.y; v[6]=c1.z; v[7]=c1.w;
      sort512(v, lane);
      float e127 = __shfl(v[7], 15);
      float e128 = __shfl(v[0], 16);
      float e255 = __shfl(v[7], 31);
      float e383 = __shfl(v[7], 47);
      float e384 = __shfl(v[0], 48);
      if (lane == 0) {
        float q25 = e127 + 0.75f * (e128 - e127);   // 0.25*(n-1)=127.75
        float q75 = e383 + 0.25f * (e384 - e383);   // 0.75*(n-1)=383.25
        lds[MEDO + s] = e255;                       // torch lower-median
        lds[STDO + s] = q75 - q25 + 1e-6f;
      }
    }
  }
  __syncthreads();

  if (tid < 12) {
    int dloc = tid / 6;
    float a = lds[STDO + 12 + dloc] / lds[STDO + tid];
    lds[SAO + tid] = a;
    lds[SCO + tid] = lds[MEDO + 12 + dloc] - lds[MEDO + tid] * a;
  }
  __syncthreads();

  const float PSC = 0.58912435f;   // (1/sqrt(6)) * log2(e)

  // ---- affine map + err (bf16 to global) + packed attn rows in regs ----
  float4 packed[2][2];
  #pragma unroll
  for (int dli = 0; dli < 2; ++dli) {
    int cb = dli * 6;
    float a0 = lds[SAO+cb+0], a1 = lds[SAO+cb+1], a2 = lds[SAO+cb+2];
    float a3 = lds[SAO+cb+3], a4 = lds[SAO+cb+4], a5 = lds[SAO+cb+5];
    float c0 = lds[SCO+cb+0], c1 = lds[SCO+cb+1], c2 = lds[SCO+cb+2];
    float c3 = lds[SCO+cb+3], c4 = lds[SCO+cb+4], c5 = lds[SCO+cb+5];
    #pragma unroll
    for (int it = 0; it < 2; ++it) {
      int l = tid + it * 256;
      float m0 = a0 * lds[XD0 + (cb + 0) * CSTR2 + l] + c0;
      float m1 = a1 * lds[XD0 + (cb + 1) * CSTR2 + l] + c1;
      float m2 = a2 * lds[XD0 + (cb + 2) * CSTR2 + l] + c2;
      float m3 = a3 * lds[XD0 + (cb + 3) * CSTR2 + l] + c3;
      float m4 = a4 * lds[XD0 + (cb + 4) * CSTR2 + l] + c4;
      float m5 = a5 * lds[XD0 + (cb + 5) * CSTR2 + l] + c5;
      float xvv = lds[XV0 + dli * CSTR2 + l];
      errb[(size_t)((b << 5) | (d0 + dli)) * LL + l] =
          f2bf(xvv - (m0 + m1 + m2 + m3 + m4 + m5) * (1.0f / 6.0f));
      packed[it][dli].x = asF(__builtin_amdgcn_cvt_pkrtz(m0 * PSC, m1 * PSC));
      packed[it][dli].y = asF(__builtin_amdgcn_cvt_pkrtz(m2 * PSC, m3 * PSC));
      packed[it][dli].z = asF(__builtin_amdgcn_cvt_pkrtz(m4 * PSC, m5 * PSC));
      packed[it][dli].w = asF(__builtin_amdgcn_cvt_pkrtz(xvv, 0.0f));
    }
  }
  __syncthreads();   // all XD/XV reads done; safe to overlay with PK

  #pragma unroll
  for (int it = 0; it < 2; ++it) {
    int l = tid + it * 256;
    *(float4*)&lds[PK + 0 * 2048 + l * 4] = packed[it][0];
    *(float4*)&lds[PK + 1 * 2048 + l * 4] = packed[it][1];
  }
  __syncthreads();

  // ---- attention: wave = (dl, l-half). 256 l x 192 o per wave ----
  {
    float askw[6], cskw[6];
    #pragma unroll
    for (int k = 0; k < 6; ++k) {
      askw[k] = lds[SAO + dl * 6 + k];
      cskw[k] = lds[SCO + dl * 6 + k];
    }
    h2 yk[3][3];
    #pragma unroll
    for (int j = 0; j < 3; ++j) {
      float q0 = askw[0] * yr[j][0].x + cskw[0];
      float q1 = askw[1] * yr[j][0].y + cskw[1];
      float q2 = askw[2] * yr[j][1].x + cskw[2];
      float q3 = askw[3] * yr[j][1].y + cskw[3];
      float q4 = askw[4] * yr[j][2].x + cskw[4];
      float q5 = askw[5] * yr[j][2].y + cskw[5];
      if (half == 0)
        ymean[(size_t)((b << 5) | dme) * OO + (lane + 64 * j)] =
            (q0 + q1 + q2 + q3 + q4 + q5) * (1.0f / 6.0f);
      yk[j][0] = __builtin_amdgcn_cvt_pkrtz(q0, q1);
      yk[j][1] = __builtin_amdgcn_cvt_pkrtz(q2, q3);
      yk[j][2] = __builtin_amdgcn_cvt_pkrtz(q4, q5);
    }

    float den[3] = {0.f, 0.f, 0.f}, num[3] = {0.f, 0.f, 0.f};
    const float* pk = &lds[PK + dl * 2048 + half * 1024];
    #pragma unroll 4
    for (int l = 0; l < 256; ++l) {
      float4 rw = *(const float4*)&pk[l * 4];   // wave-uniform broadcast
      h2 x01 = asH(rw.x), x23 = asH(rw.y), x45 = asH(rw.z);
      float xf = (float)(asH(rw.w).x);
      #pragma unroll
      for (int j = 0; j < 3; ++j) {
        float sc = __builtin_amdgcn_fdot2(x01, yk[j][0], 0.0f, false);
        sc = __builtin_amdgcn_fdot2(x23, yk[j][1], sc, false);
        sc = __builtin_amdgcn_fdot2(x45, yk[j][2], sc, false);
        float e = exp2f(sc);     // scale folded into x-side pack
        den[j] += e;
        num[j] += e * xf;
      }
    }
    #pragma unroll
    for (int j = 0; j < 3; ++j) {
      lds[DENB + wv * 192 + lane + 64 * j] = den[j];
      lds[NUMB + wv * 192 + lane + 64 * j] = num[j];
    }
  }
  __syncthreads();

  // ---- combine halves, V write, bn partials ----
  float s1v[2] = {0.f, 0.f}, s2v[2] = {0.f, 0.f};
  if (tid < OO) {
    #pragma unroll
    for (int dli = 0; dli < 2; ++dli) {
      float den = lds[DENB + dli * 384 + tid] + lds[DENB + dli * 384 + 192 + tid];
      float num = lds[NUMB + dli * 384 + tid] + lds[NUMB + dli * 384 + 192 + tid];
      float vv = num / den;
      V[(size_t)((b << 5) | (d0 + dli)) * OO + tid] = vv;
      s1v[dli] = vv; s2v[dli] = vv * vv;
    }
  }
  #pragma unroll
  for (int off = 32; off > 0; off >>= 1) {
    s1v[0] += __shfl_down(s1v[0], off);
    s1v[1] += __shfl_down(s1v[1], off);
    s2v[0] += __shfl_down(s2v[0], off);
    s2v[1] += __shfl_down(s2v[1], off);
  }
  if (lane == 0) {
    lds[BNR + 0  + wv] = s1v[0];
    lds[BNR + 4  + wv] = s1v[1];
    lds[BNR + 8  + wv] = s2v[0];
    lds[BNR + 12 + wv] = s2v[1];
  }
  __syncthreads();
  if (tid == 0) {
    #pragma unroll
    for (int dli = 0; dli < 2; ++dli) {
      float S  = lds[BNR + dli * 4 + 0] + lds[BNR + dli * 4 + 1]
               + lds[BNR + dli * 4 + 2] + lds[BNR + dli * 4 + 3];
      float S2 = lds[BNR + 8 + dli * 4 + 0] + lds[BNR + 8 + dli * 4 + 1]
               + lds[BNR + 8 + dli * 4 + 2] + lds[BNR + 8 + dli * 4 + 3];
      bnp[((d0 + dli) << 5) | b]          = S;   // no atomics: per-(d,b)
      bnp[1024 + (((d0 + dli) << 5) | b)] = S2;
    }
  }
}

// ---------------------------------------------------------------------------
// K2 tail: 256 blocks = (b, o-eighth of 24). Each block REDUNDANTLY computes
// its b's 32-row gating GEMM via MFMA (w1t is L2-resident), bn constants from
// bnp partials, then the final fusion for its 24 o's.
// ---------------------------------------------------------------------------
__global__ __launch_bounds__(256) void tail_kernel(
    const unsigned short* __restrict__ errb, const unsigned short* __restrict__ w1t,
    const float* __restrict__ b1, const float* __restrict__ w2,
    const float* __restrict__ b2, const float* __restrict__ V,
    const float* __restrict__ ymean, const float* __restrict__ bnp,
    const float* __restrict__ gamma, const float* __restrict__ beta,
    float* __restrict__ out) {
  __shared__ float vsh[32 * 28], ysh[32 * 28];
  __shared__ float part[4][32];
  __shared__ float gsh[32], ssh[32], osh[32];
  int g = blockIdx.x, tid = threadIdx.x;
  int b = g >> 3, o0 = (g & 7) * 24;
  int lane = tid & 63, wv = tid >> 6;
  int m16 = lane & 15, quad = lane >> 4;
  int mw = wv * 128;
  int r0 = b * 32;

  // ---- stage V/ymean for (b, o-slice): 32 d x 6 float4 ----
  if (tid < 192) {
    int dd = tid / 6, c4 = tid % 6;
    size_t goff = (size_t)(b * DD + dd) * OO + o0;
    float4 v = ((const float4*)(V + goff))[c4];
    float4 y = ((const float4*)(ymean + goff))[c4];
    *(float4*)&vsh[dd * 28 + c4 * 4] = v;
    *(float4*)&ysh[dd * 28 + c4 * 4] = y;
  }

  // ---- gating GEMM: rows r0..r0+31 x all 512 m (wave: 128 m) ----
  float b1v[8], w2d[8];
  #pragma unroll
  for (int ct = 0; ct < 8; ++ct) {
    int m = mw + ct * 16 + m16;
    b1v[ct] = b1[m];
    float2 w2p = ((const float2*)w2)[m];
    w2d[ct] = w2p.x - w2p.y;
  }

  f4 acc[2][8];
  #pragma unroll
  for (int rt = 0; rt < 2; ++rt)
    #pragma unroll
    for (int ct = 0; ct < 8; ++ct)
      acc[rt][ct] = (f4){0.f, 0.f, 0.f, 0.f};

  const unsigned short* ea = errb + (size_t)(r0 + m16) * DM + quad * 8;
  const unsigned short* eb = ea + 16 * DM;
  const unsigned short* wb = w1t + (size_t)(mw + m16) * DM + quad * 8;

  for (int ks = 0; ks < DM; ks += 32) {
    U16x8 ua0, ua1;
    ua0.u = *(const uint4*)(ea + ks);
    ua1.u = *(const uint4*)(eb + ks);
    #pragma unroll
    for (int ct = 0; ct < 8; ++ct) {
      U16x8 ub;
      ub.u = *(const uint4*)(wb + (size_t)ct * 16 * DM + ks);
      acc[0][ct] = __builtin_amdgcn_mfma_f32_16x16x32_bf16(ua0.h, ub.h, acc[0][ct], 0, 0, 0);
      acc[1][ct] = __builtin_amdgcn_mfma_f32_16x16x32_bf16(ua1.h, ub.h, acc[1][ct], 0, 0, 0);
    }
  }

  #pragma unroll
  for (int rt = 0; rt < 2; ++rt) {
    float rsum[4] = {0.f, 0.f, 0.f, 0.f};
    #pragma unroll
    for (int ct = 0; ct < 8; ++ct) {
      #pragma unroll
      for (int r = 0; r < 4; ++r) {
        float h = acc[rt][ct][r] + b1v[ct];
        float gg = 0.5f * h * (1.0f + erff(h * 0.70710678f));
        rsum[r] += gg * w2d[ct];
      }
    }
    #pragma unroll
    for (int r = 0; r < 4; ++r) {
      rsum[r] += __shfl_xor(rsum[r], 1);
      rsum[r] += __shfl_xor(rsum[r], 2);
      rsum[r] += __shfl_xor(rsum[r], 4);
      rsum[r] += __shfl_xor(rsum[r], 8);
    }
    if (m16 == 0) {
      #pragma unroll
      for (int r = 0; r < 4; ++r)
        part[wv][rt * 16 + quad * 4 + r] = rsum[r];
    }
  }
  __syncthreads();

  if (tid < 32) {
    float ld = b2[0] - b2[1]
             + part[0][tid] + part[1][tid] + part[2][tid] + part[3][tid];
    gsh[tid] = 1.0f / (1.0f + expf(-ld));      // gate w0 for (b, d=tid)
    float S = 0.f, S2 = 0.f;
    const float* pd = bnp + (tid << 5);
    #pragma unroll 8
    for (int bb = 0; bb < 32; ++bb) { S += pd[bb]; S2 += pd[1024 + bb]; }
    const float inv = 1.0f / (BB * OO);
    float mu = S * inv;
    float var = S2 * inv - mu * mu;
    float gg = gamma[tid] * rsqrtf(var + 1e-5f);
    ssh[tid] = gg;
    osh[tid] = beta[tid] - mu * gg;
  }
  __syncthreads();

  // ---- final fusion: 24 o x 8 float4 (32 d), coalesced out writes ----
  if (tid < 192) {
    int op = tid >> 3, c4 = tid & 7;
    float4 r;
    #pragma unroll
    for (int j = 0; j < 4; ++j) {
      int dd = c4 * 4 + j;
      float v  = vsh[dd * 28 + op];
      float ym = ysh[dd * 28 + op];
      float gg = gsh[dd];
      float y  = v * ssh[dd] + osh[dd];
      ((float*)&r)[j] = ym * gg + y * (1.0f - gg);
    }
    ((float4*)(out + (size_t)(b * OO + o0 + op) * DD))[c4] = r;
  }
}

// ---------------------------------------------------------------------------
extern "C" void kernel_launch(void* const* d_in, const int* in_sizes, int n_in,
                              void* d_out, int out_size, void* d_ws, size_t ws_size,
                              hipStream_t stream) {
  const float* x      = (const float*)d_in[0];
  const float* x_date = (const float*)d_in[1];
  const float* y_date = (const float*)d_in[2];
  const float* w1     = (const float*)d_in[3];
  const float* b1     = (const float*)d_in[4];
  const float* w2     = (const float*)d_in[5];
  const float* b2     = (const float*)d_in[6];
  const float* gamma  = (const float*)d_in[7];
  const float* beta   = (const float*)d_in[8];
  float* out = (float*)d_out;

  float* ws    = (float*)d_ws;
  float* V     = ws;                             // [0, 196608)   (B,D,O)
  float* ymean = ws + 196608;                    // [196608, 393216)
  float* bnp   = ws + 393216;                    // [393216, 395264)
  unsigned short* errb = (unsigned short*)(ws + 395264);   // [395264, 657408) 1024x512 bf16
  unsigned short* w1t  = (unsigned short*)(ws + 657408);   // [657408, 788480) 512x512 bf16 (m,l)

  fused_kernel<<<576, 256, 0, stream>>>(x, x_date, y_date, w1,
                                        V, ymean, bnp, errb, w1t);
  tail_kernel<<<256, 256, 0, stream>>>(errb, w1t, b1, w2, b2, V, ymean,
                                       bnp, gamma, beta, out);
}

// Round 9
// 145.733 us; speedup vs baseline: 1.1775x; 1.0994x over previous
//
#include <hip/hip_runtime.h>
#include <math.h>

#define BB 32
#define LL 512
#define DD 32
#define KK 6
#define OO 192
#define DM 512

typedef __fp16 h2 __attribute__((ext_vector_type(2)));
union F2H { float f; h2 h; };
__device__ __forceinline__ float asF(h2 h) { F2H u; u.h = h; return u.f; }
__device__ __forceinline__ h2 asH(float f) { F2H u; u.f = f; return u.h; }

typedef short bf16x8 __attribute__((ext_vector_type(8)));
typedef float f4 __attribute__((ext_vector_type(4)));
union U16x8 { uint4 u; bf16x8 h; };

__device__ __forceinline__ unsigned short f2bf(float x) {   // RNE f32->bf16
  unsigned int u = __float_as_uint(x);
  u = (u + 0x7FFF + ((u >> 16) & 1)) >> 16;
  return (unsigned short)u;
}

#define MOVDPP(x, ctrl) \
  __int_as_float(__builtin_amdgcn_mov_dpp(__float_as_int(x), ctrl, 0xf, 0xf, true))

// LDS layout (float slots), d-pair blocks, COLUMN-MAJOR x/x_date storage.
// CSTR2=524: 16B-aligned columns (sort gather = conflict-free b128),
// and 4*524 % 32 == 16 -> transpose-writes ~2-way (free).
#define CSTR2 524
#define XD0   0                  // 12 cols x 524           (6288)
#define XV0   6288               // 2 cols x 524            (1048) -> 7336
#define MEDO  7336               // 14
#define STDO  7350               // 14
#define SAO   7364               // 12
#define SCO   7376               // 12
#define BNR   7388               // 16 bn wave partials
#define PK    0                  // overlay: packed rows [2][512][4] (4096)
#define DENB  4200               // overlay: [4 wv][192]     (768)
#define NUMB  4968               // overlay: [4 wv][192]     (768) -> 5736 < 6288
#define LDSF  7404               // 29.6 KB

// ---------------------------------------------------------------------------
// In-register bitonic sort of 512 floats across one wave (8 elems/lane).
// ---------------------------------------------------------------------------
__device__ __forceinline__ void sort512(float v[8], int lane) {
  #pragma unroll
  for (int k = 2; k <= 512; k <<= 1) {
    #pragma unroll
    for (int j = k >> 1; j > 0; j >>= 1) {
      if (j >= 8) {
        int jj = j >> 3;
        bool lower = (lane & jj) == 0;
        bool asc = ((lane << 3) & k) == 0;
        bool keepmin = (asc == lower);
        #pragma unroll
        for (int r = 0; r < 8; ++r) {
          float o;
          if (jj == 1)      o = MOVDPP(v[r], 0xB1);   // quad_perm [1,0,3,2]
          else if (jj == 2) o = MOVDPP(v[r], 0x4E);   // quad_perm [2,3,0,1]
          else if (jj == 8) o = MOVDPP(v[r], 0x128);  // row_ror:8 == xor8
          else              o = __shfl_xor(v[r], jj);
          v[r] = keepmin ? fminf(v[r], o) : fmaxf(v[r], o);
        }
      } else {
        #pragma unroll
        for (int r = 0; r < 8; ++r) {
          if ((r & j) == 0) {
            int r2 = r | j;
            bool asc = (((lane << 3) | r) & k) == 0;
            float a = v[r], b = v[r2];
            float lo = fminf(a, b), hi = fmaxf(a, b);
            v[r]  = asc ? lo : hi;
            v[r2] = asc ? hi : lo;
          }
        }
      }
    }
  }
}

// ---------------------------------------------------------------------------
// K1 fused: blocks 0..511 = (b, d-pair). Coalesced global reads, column-major
// LDS store (transpose-on-write). 14 sorts over 4 waves. Attention: wave =
// (d of pair, l-half), LDS den/num combine. Blocks 512..575: w1 -> w1t bf16.
// (verbatim R7 — measured 63.9 us, conflicts 213K)
// ---------------------------------------------------------------------------
__global__ __launch_bounds__(256) void fused_kernel(
    const float* __restrict__ x, const float* __restrict__ x_date,
    const float* __restrict__ y_date, const float* __restrict__ w1,
    float* __restrict__ V, float* __restrict__ ymean,
    float* __restrict__ bnp, unsigned short* __restrict__ errb,
    unsigned short* __restrict__ w1t) {
  __shared__ float lds[LDSF];
  int orig = blockIdx.x;
  int tid = threadIdx.x, lane = tid & 63, wv = tid >> 6;

  if (orig >= 512) {
    // ---- w1 -> w1t bf16, 64x64 tile (independent of main path) ----
    float* tw = lds;                           // 64*68 = 4352 floats
    int id = orig - 512;                       // 0..63
    int l0 = (id & 7) * 64, m0 = (id >> 3) * 64;
    #pragma unroll
    for (int it = 0; it < 4; ++it) {           // 64 l-rows x 16 float4
      int f = tid + it * 256;
      int row = f >> 4, c4 = f & 15;
      float4 v = ((const float4*)(w1 + (size_t)(l0 + row) * DM + m0))[c4];
      float* p = &tw[row * 68 + c4 * 4];
      p[0] = v.x; p[1] = v.y; p[2] = v.z; p[3] = v.w;
    }
    __syncthreads();
    unsigned int* w1t32 = (unsigned int*)w1t;
    #pragma unroll
    for (int it = 0; it < 8; ++it) {           // 64 m-rows x 32 uints
      int f = tid + it * 256;
      int mr = f >> 5, c = f & 31;
      float a = tw[(c * 2 + 0) * 68 + mr];
      float b = tw[(c * 2 + 1) * 68 + mr];
      unsigned int u = (unsigned int)f2bf(a) | ((unsigned int)f2bf(b) << 16);
      w1t32[(size_t)(m0 + mr) * (DM / 2) + (l0 >> 1) + c] = u;
    }
    return;
  }

  // XCD-aware swizzle: 64 blocks per XCD = 4 b's x 16 d-pairs.
  int xcd = orig & 7, idx = orig >> 3;         // idx 0..63
  int b = (xcd << 2) | (idx >> 4);
  int d0 = (idx & 15) << 1;                    // pair base d

  // ---- coalesced read + transpose-on-write: x_date rows (3 float4) ----
  const float* xs = x_date + (size_t)b * LL * 192 + d0 * 6;
  #pragma unroll
  for (int it = 0; it < 6; ++it) {             // 512 rows x 3 float4
    int f = tid + it * 256;
    int row = f / 3, c4 = f % 3;
    float4 v = ((const float4*)(xs + (size_t)row * 192))[c4];
    int col = c4 * 4;
    lds[XD0 + (col + 0) * CSTR2 + row] = v.x;
    lds[XD0 + (col + 1) * CSTR2 + row] = v.y;
    lds[XD0 + (col + 2) * CSTR2 + row] = v.z;
    lds[XD0 + (col + 3) * CSTR2 + row] = v.w;
  }
  #pragma unroll
  for (int it = 0; it < 2; ++it) {             // 512 rows x float2 (2 d's)
    int row = tid + it * 256;
    float2 v = *(const float2*)(x + (size_t)(b * LL + row) * DD + d0);
    lds[XV0 + row]         = v.x;
    lds[XV0 + CSTR2 + row] = v.y;
  }

  // ---- prefetch this wave's y_date column (d = d0 + (wv>>1)) ----
  int dl = wv >> 1, half = wv & 1;
  int dme = d0 + dl;
  float2 yr[3][3];
  #pragma unroll
  for (int j = 0; j < 3; ++j) {
    const float2* yp = (const float2*)(
        y_date + (((size_t)b * OO + (lane + 64 * j)) * DD + dme) * KK);
    yr[j][0] = yp[0]; yr[j][1] = yp[1]; yr[j][2] = yp[2];
  }
  __syncthreads();

  // ---- 14 sorts: 4 rounds x 4 waves.  s<12: x_date col, s>=12: x col ----
  for (int p = 0; p < 4; ++p) {
    int s = p * 4 + wv;
    if (s < 14) {
      const float4* colp = (s < 12)
          ? (const float4*)&lds[XD0 + s * CSTR2 + lane * 8]
          : (const float4*)&lds[XV0 + (s - 12) * CSTR2 + lane * 8];
      float v[8];
      float4 c0 = colp[0], c1 = colp[1];
      v[0]=c0.x; v[1]=c0.y; v[2]=c0.z; v[3]=c0.w;
      v[4]=c1.x; v[5]=c1.y; v[6]=c1.z; v[7]=c1.w;
      sort512(v, lane);
      float e127 = __shfl(v[7], 15);
      float e128 = __shfl(v[0], 16);
      float e255 = __shfl(v[7], 31);
      float e383 = __shfl(v[7], 47);
      float e384 = __shfl(v[0], 48);
      if (lane == 0) {
        float q25 = e127 + 0.75f * (e128 - e127);   // 0.25*(n-1)=127.75
        float q75 = e383 + 0.25f * (e384 - e383);   // 0.75*(n-1)=383.25
        lds[MEDO + s] = e255;                       // torch lower-median
        lds[STDO + s] = q75 - q25 + 1e-6f;
      }
    }
  }
  __syncthreads();

  if (tid < 12) {
    int dloc = tid / 6;
    float a = lds[STDO + 12 + dloc] / lds[STDO + tid];
    lds[SAO + tid] = a;
    lds[SCO + tid] = lds[MEDO + 12 + dloc] - lds[MEDO + tid] * a;
  }
  __syncthreads();

  const float PSC = 0.58912435f;   // (1/sqrt(6)) * log2(e)

  // ---- affine map + err (bf16 to global) + packed attn rows in regs ----
  float4 packed[2][2];
  #pragma unroll
  for (int dli = 0; dli < 2; ++dli) {
    int cb = dli * 6;
    float a0 = lds[SAO+cb+0], a1 = lds[SAO+cb+1], a2 = lds[SAO+cb+2];
    float a3 = lds[SAO+cb+3], a4 = lds[SAO+cb+4], a5 = lds[SAO+cb+5];
    float c0 = lds[SCO+cb+0], c1 = lds[SCO+cb+1], c2 = lds[SCO+cb+2];
    float c3 = lds[SCO+cb+3], c4 = lds[SCO+cb+4], c5 = lds[SCO+cb+5];
    #pragma unroll
    for (int it = 0; it < 2; ++it) {
      int l = tid + it * 256;
      float m0 = a0 * lds[XD0 + (cb + 0) * CSTR2 + l] + c0;
      float m1 = a1 * lds[XD0 + (cb + 1) * CSTR2 + l] + c1;
      float m2 = a2 * lds[XD0 + (cb + 2) * CSTR2 + l] + c2;
      float m3 = a3 * lds[XD0 + (cb + 3) * CSTR2 + l] + c3;
      float m4 = a4 * lds[XD0 + (cb + 4) * CSTR2 + l] + c4;
      float m5 = a5 * lds[XD0 + (cb + 5) * CSTR2 + l] + c5;
      float xvv = lds[XV0 + dli * CSTR2 + l];
      errb[(size_t)((b << 5) | (d0 + dli)) * LL + l] =
          f2bf(xvv - (m0 + m1 + m2 + m3 + m4 + m5) * (1.0f / 6.0f));
      packed[it][dli].x = asF(__builtin_amdgcn_cvt_pkrtz(m0 * PSC, m1 * PSC));
      packed[it][dli].y = asF(__builtin_amdgcn_cvt_pkrtz(m2 * PSC, m3 * PSC));
      packed[it][dli].z = asF(__builtin_amdgcn_cvt_pkrtz(m4 * PSC, m5 * PSC));
      packed[it][dli].w = asF(__builtin_amdgcn_cvt_pkrtz(xvv, 0.0f));
    }
  }
  __syncthreads();   // all XD/XV reads done; safe to overlay with PK

  #pragma unroll
  for (int it = 0; it < 2; ++it) {
    int l = tid + it * 256;
    *(float4*)&lds[PK + 0 * 2048 + l * 4] = packed[it][0];
    *(float4*)&lds[PK + 1 * 2048 + l * 4] = packed[it][1];
  }
  __syncthreads();

  // ---- attention: wave = (dl, l-half). 256 l x 192 o per wave ----
  {
    float askw[6], cskw[6];
    #pragma unroll
    for (int k = 0; k < 6; ++k) {
      askw[k] = lds[SAO + dl * 6 + k];
      cskw[k] = lds[SCO + dl * 6 + k];
    }
    h2 yk[3][3];
    #pragma unroll
    for (int j = 0; j < 3; ++j) {
      float q0 = askw[0] * yr[j][0].x + cskw[0];
      float q1 = askw[1] * yr[j][0].y + cskw[1];
      float q2 = askw[2] * yr[j][1].x + cskw[2];
      float q3 = askw[3] * yr[j][1].y + cskw[3];
      float q4 = askw[4] * yr[j][2].x + cskw[4];
      float q5 = askw[5] * yr[j][2].y + cskw[5];
      if (half == 0)
        ymean[(size_t)((b << 5) | dme) * OO + (lane + 64 * j)] =
            (q0 + q1 + q2 + q3 + q4 + q5) * (1.0f / 6.0f);
      yk[j][0] = __builtin_amdgcn_cvt_pkrtz(q0, q1);
      yk[j][1] = __builtin_amdgcn_cvt_pkrtz(q2, q3);
      yk[j][2] = __builtin_amdgcn_cvt_pkrtz(q4, q5);
    }

    float den[3] = {0.f, 0.f, 0.f}, num[3] = {0.f, 0.f, 0.f};
    const float* pk = &lds[PK + dl * 2048 + half * 1024];
    #pragma unroll 4
    for (int l = 0; l < 256; ++l) {
      float4 rw = *(const float4*)&pk[l * 4];   // wave-uniform broadcast
      h2 x01 = asH(rw.x), x23 = asH(rw.y), x45 = asH(rw.z);
      float xf = (float)(asH(rw.w).x);
      #pragma unroll
      for (int j = 0; j < 3; ++j) {
        float sc = __builtin_amdgcn_fdot2(x01, yk[j][0], 0.0f, false);
        sc = __builtin_amdgcn_fdot2(x23, yk[j][1], sc, false);
        sc = __builtin_amdgcn_fdot2(x45, yk[j][2], sc, false);
        float e = exp2f(sc);     // scale folded into x-side pack
        den[j] += e;
        num[j] += e * xf;
      }
    }
    #pragma unroll
    for (int j = 0; j < 3; ++j) {
      lds[DENB + wv * 192 + lane + 64 * j] = den[j];
      lds[NUMB + wv * 192 + lane + 64 * j] = num[j];
    }
  }
  __syncthreads();

  // ---- combine halves, V write, bn partials ----
  float s1v[2] = {0.f, 0.f}, s2v[2] = {0.f, 0.f};
  if (tid < OO) {
    #pragma unroll
    for (int dli = 0; dli < 2; ++dli) {
      float den = lds[DENB + dli * 384 + tid] + lds[DENB + dli * 384 + 192 + tid];
      float num = lds[NUMB + dli * 384 + tid] + lds[NUMB + dli * 384 + 192 + tid];
      float vv = num / den;
      V[(size_t)((b << 5) | (d0 + dli)) * OO + tid] = vv;
      s1v[dli] = vv; s2v[dli] = vv * vv;
    }
  }
  #pragma unroll
  for (int off = 32; off > 0; off >>= 1) {
    s1v[0] += __shfl_down(s1v[0], off);
    s1v[1] += __shfl_down(s1v[1], off);
    s2v[0] += __shfl_down(s2v[0], off);
    s2v[1] += __shfl_down(s2v[1], off);
  }
  if (lane == 0) {
    lds[BNR + 0  + wv] = s1v[0];
    lds[BNR + 4  + wv] = s1v[1];
    lds[BNR + 8  + wv] = s2v[0];
    lds[BNR + 12 + wv] = s2v[1];
  }
  __syncthreads();
  if (tid == 0) {
    #pragma unroll
    for (int dli = 0; dli < 2; ++dli) {
      float S  = lds[BNR + dli * 4 + 0] + lds[BNR + dli * 4 + 1]
               + lds[BNR + dli * 4 + 2] + lds[BNR + dli * 4 + 3];
      float S2 = lds[BNR + 8 + dli * 4 + 0] + lds[BNR + 8 + dli * 4 + 1]
               + lds[BNR + 8 + dli * 4 + 2] + lds[BNR + 8 + dli * 4 + 3];
      bnp[((d0 + dli) << 5) | b]          = S;   // no atomics: per-(d,b)
      bnp[1024 + (((d0 + dli) << 5) | b)] = S2;
    }
  }
}

// ---------------------------------------------------------------------------
// K2 gate: 256 blocks = (b, m-slice of 64). NO redundancy: each block computes
// h[m] = err_b,d . w1[:,m] for its 64 m's x all 32 d via MFMA, applies gelu
// and the w2 contraction, and writes a 32-float partial logit per (b,slice).
// Splitting over m is exact (gelu applies per-m to a COMPLETE h[m]).
// ---------------------------------------------------------------------------
__global__ __launch_bounds__(256) void gate_kernel(
    const unsigned short* __restrict__ errb, const unsigned short* __restrict__ w1t,
    const float* __restrict__ b1, const float* __restrict__ w2,
    float* __restrict__ gatep) {
  __shared__ float part[4][32];
  int orig = blockIdx.x;
  // colocate with the XCD that produced errb[b] (fused: xcd = b>>2)
  int xcd = orig & 7, idx = orig >> 3;         // idx 0..31
  int b = (xcd << 2) | (idx >> 3);
  int s = idx & 7;                             // m-slice
  int tid = threadIdx.x, lane = tid & 63, wv = tid >> 6;
  int m16 = lane & 15, quad = lane >> 4;
  int mw = s * 64 + wv * 16;                   // this wave's 16 m's
  int r0 = b * 32;

  float b1v = b1[mw + m16];
  float2 w2p = ((const float2*)w2)[mw + m16];
  float w2d = w2p.x - w2p.y;

  f4 acc[2];
  acc[0] = (f4){0.f, 0.f, 0.f, 0.f};
  acc[1] = (f4){0.f, 0.f, 0.f, 0.f};

  const unsigned short* ea = errb + (size_t)(r0 + m16) * DM + quad * 8;
  const unsigned short* eb = ea + 16 * DM;
  const unsigned short* wb = w1t + (size_t)(mw + m16) * DM + quad * 8;

  #pragma unroll
  for (int ks = 0; ks < DM; ks += 32) {
    U16x8 ua0, ua1, ub;
    ua0.u = *(const uint4*)(ea + ks);
    ua1.u = *(const uint4*)(eb + ks);
    ub.u  = *(const uint4*)(wb + ks);
    acc[0] = __builtin_amdgcn_mfma_f32_16x16x32_bf16(ua0.h, ub.h, acc[0], 0, 0, 0);
    acc[1] = __builtin_amdgcn_mfma_f32_16x16x32_bf16(ua1.h, ub.h, acc[1], 0, 0, 0);
  }

  // lane (m16, quad): acc[rt][r] = h[d = rt*16 + quad*4 + r][m = mw + m16]
  float rsum[2][4];
  #pragma unroll
  for (int rt = 0; rt < 2; ++rt) {
    #pragma unroll
    for (int r = 0; r < 4; ++r) {
      float h = acc[rt][r] + b1v;
      float gg = 0.5f * h * (1.0f + erff(h * 0.70710678f));
      rsum[rt][r] = gg * w2d;
    }
  }
  #pragma unroll
  for (int rt = 0; rt < 2; ++rt) {
    #pragma unroll
    for (int r = 0; r < 4; ++r) {
      rsum[rt][r] += __shfl_xor(rsum[rt][r], 1);
      rsum[rt][r] += __shfl_xor(rsum[rt][r], 2);
      rsum[rt][r] += __shfl_xor(rsum[rt][r], 4);
      rsum[rt][r] += __shfl_xor(rsum[rt][r], 8);
    }
  }
  if (m16 == 0) {
    #pragma unroll
    for (int rt = 0; rt < 2; ++rt)
      #pragma unroll
      for (int r = 0; r < 4; ++r)
        part[wv][rt * 16 + quad * 4 + r] = rsum[rt][r];
  }
  __syncthreads();

  if (tid < 32) {
    float p = part[0][tid] + part[1][tid] + part[2][tid] + part[3][tid];
    gatep[(size_t)(((b << 3) | s) << 5) | tid] = p;   // partial for (b, d=tid)
  }
}

// ---------------------------------------------------------------------------
// K3 tail: 256 blocks = (b, o-eighth of 24). Pure elementwise now: sum the 8
// gate partials, bn constants from bnp, gated fusion, coalesced out writes.
// ---------------------------------------------------------------------------
__global__ __launch_bounds__(256) void tail_kernel(
    const float* __restrict__ gatep, const float* __restrict__ b2,
    const float* __restrict__ V, const float* __restrict__ ymean,
    const float* __restrict__ bnp,
    const float* __restrict__ gamma, const float* __restrict__ beta,
    float* __restrict__ out) {
  __shared__ float vsh[32 * 28], ysh[32 * 28];
  __shared__ float gsh[32], ssh[32], osh[32];
  int g = blockIdx.x, tid = threadIdx.x;
  // colocate with the XCD that produced V/ymean/gatep for this b
  int xcd = g & 7, idx = g >> 3;
  int b = (xcd << 2) | (idx >> 3);
  int o0 = (idx & 7) * 24;

  // ---- stage V/ymean for (b, o-slice): 32 d x 6 float4 ----
  if (tid < 192) {
    int dd = tid / 6, c4 = tid % 6;
    size_t goff = (size_t)(b * DD + dd) * OO + o0;
    float4 v = ((const float4*)(V + goff))[c4];
    float4 y = ((const float4*)(ymean + goff))[c4];
    *(float4*)&vsh[dd * 28 + c4 * 4] = v;
    *(float4*)&ysh[dd * 28 + c4 * 4] = y;
  }

  if (tid < 32) {
    float ld = b2[0] - b2[1];
    #pragma unroll
    for (int s = 0; s < 8; ++s)
      ld += gatep[(size_t)(((b << 3) | s) << 5) | tid];
    gsh[tid] = 1.0f / (1.0f + expf(-ld));      // gate w0 for (b, d=tid)
    float S = 0.f, S2 = 0.f;
    const float* pd = bnp + (tid << 5);
    #pragma unroll 8
    for (int bb = 0; bb < 32; ++bb) { S += pd[bb]; S2 += pd[1024 + bb]; }
    const float inv = 1.0f / (BB * OO);
    float mu = S * inv;
    float var = S2 * inv - mu * mu;
    float gg = gamma[tid] * rsqrtf(var + 1e-5f);
    ssh[tid] = gg;
    osh[tid] = beta[tid] - mu * gg;
  }
  __syncthreads();

  // ---- final fusion: 24 o x 8 float4 (32 d), coalesced out writes ----
  if (tid < 192) {
    int op = tid >> 3, c4 = tid & 7;
    float4 r;
    #pragma unroll
    for (int j = 0; j < 4; ++j) {
      int dd = c4 * 4 + j;
      float v  = vsh[dd * 28 + op];
      float ym = ysh[dd * 28 + op];
      float gg = gsh[dd];
      float y  = v * ssh[dd] + osh[dd];
      ((float*)&r)[j] = ym * gg + y * (1.0f - gg);
    }
    ((float4*)(out + (size_t)(b * OO + o0 + op) * DD))[c4] = r;
  }
}

// ---------------------------------------------------------------------------
extern "C" void kernel_launch(void* const* d_in, const int* in_sizes, int n_in,
                              void* d_out, int out_size, void* d_ws, size_t ws_size,
                              hipStream_t stream) {
  const float* x      = (const float*)d_in[0];
  const float* x_date = (const float*)d_in[1];
  const float* y_date = (const float*)d_in[2];
  const float* w1     = (const float*)d_in[3];
  const float* b1     = (const float*)d_in[4];
  const float* w2     = (const float*)d_in[5];
  const float* b2     = (const float*)d_in[6];
  const float* gamma  = (const float*)d_in[7];
  const float* beta   = (const float*)d_in[8];
  float* out = (float*)d_out;

  float* ws    = (float*)d_ws;
  float* V     = ws;                             // [0, 196608)   (B,D,O)
  float* ymean = ws + 196608;                    // [196608, 393216)
  float* bnp   = ws + 393216;                    // [393216, 395264)
  unsigned short* errb = (unsigned short*)(ws + 395264);   // [395264, 657408) 1024x512 bf16
  unsigned short* w1t  = (unsigned short*)(ws + 657408);   // [657408, 788480) 512x512 bf16 (m,l)
  float* gatep = ws + 788480;                    // [788480, 796672) 32b x 8s x 32d

  fused_kernel<<<576, 256, 0, stream>>>(x, x_date, y_date, w1,
                                        V, ymean, bnp, errb, w1t);
  gate_kernel<<<256, 256, 0, stream>>>(errb, w1t, b1, w2, gatep);
  tail_kernel<<<256, 256, 0, stream>>>(gatep, b2, V, ymean, bnp,
                                       gamma, beta, out);
}

// Round 10
// 142.541 us; speedup vs baseline: 1.2038x; 1.0224x over previous
//
#include <hip/hip_runtime.h>
#include <math.h>

#define BB 32
#define LL 512
#define DD 32
#define KK 6
#define OO 192
#define DM 512

typedef __fp16 h2 __attribute__((ext_vector_type(2)));
typedef __fp16 h8 __attribute__((ext_vector_type(8)));
union F2H { float f; h2 h; };
__device__ __forceinline__ float asF(h2 h) { F2H u; u.h = h; return u.f; }
__device__ __forceinline__ h2 asH(float f) { F2H u; u.f = f; return u.h; }

typedef short bf16x8 __attribute__((ext_vector_type(8)));
typedef float f4 __attribute__((ext_vector_type(4)));
union U16x8 { uint4 u; bf16x8 h; };
union UH8F { uint4 u; h8 h; };

__device__ __forceinline__ unsigned short f2bf(float x) {   // RNE f32->bf16
  unsigned int u = __float_as_uint(x);
  u = (u + 0x7FFF + ((u >> 16) & 1)) >> 16;
  return (unsigned short)u;
}

#define MOVDPP(x, ctrl) \
  __int_as_float(__builtin_amdgcn_mov_dpp(__float_as_int(x), ctrl, 0xf, 0xf, true))

// LDS layout (float slots), d-pair blocks, COLUMN-MAJOR x/x_date storage.
// CSTR2=524: 16B-aligned columns (sort gather = conflict-free b128),
// and 4*524 % 32 == 16 -> transpose-writes ~2-way (free).
#define CSTR2 524
#define XD0   0                  // 12 cols x 524           (6288)
#define XV0   6288               // 2 cols x 524            (1048) -> 7336
#define MEDO  7336               // 14
#define STDO  7350               // 14
#define SAO   7364               // 12
#define SCO   7376               // 12
#define BNR   7388               // 16 bn wave partials
// overlays of the dead XD region after the map phase:
#define XMP   0                  // Xm pack: [2 d][512 l][8 f16] = 4096 floats
#define YMP   4096               // Ym pack: [2 d][192 o][8 f16] = 1536 floats -> 5632 < 6288
#define LDSF  7404               // 29.6 KB

// ---------------------------------------------------------------------------
// In-register bitonic sort of 512 floats across one wave (8 elems/lane).
// ---------------------------------------------------------------------------
__device__ __forceinline__ void sort512(float v[8], int lane) {
  #pragma unroll
  for (int k = 2; k <= 512; k <<= 1) {
    #pragma unroll
    for (int j = k >> 1; j > 0; j >>= 1) {
      if (j >= 8) {
        int jj = j >> 3;
        bool lower = (lane & jj) == 0;
        bool asc = ((lane << 3) & k) == 0;
        bool keepmin = (asc == lower);
        #pragma unroll
        for (int r = 0; r < 8; ++r) {
          float o;
          if (jj == 1)      o = MOVDPP(v[r], 0xB1);   // quad_perm [1,0,3,2]
          else if (jj == 2) o = MOVDPP(v[r], 0x4E);   // quad_perm [2,3,0,1]
          else if (jj == 8) o = MOVDPP(v[r], 0x128);  // row_ror:8 == xor8
          else              o = __shfl_xor(v[r], jj);
          v[r] = keepmin ? fminf(v[r], o) : fmaxf(v[r], o);
        }
      } else {
        #pragma unroll
        for (int r = 0; r < 8; ++r) {
          if ((r & j) == 0) {
            int r2 = r | j;
            bool asc = (((lane << 3) | r) & k) == 0;
            float a = v[r], b = v[r2];
            float lo = fminf(a, b), hi = fmaxf(a, b);
            v[r]  = asc ? lo : hi;
            v[r2] = asc ? hi : lo;
          }
        }
      }
    }
  }
}

// ---------------------------------------------------------------------------
// K1 fused: blocks 0..511 = (b, d-pair). Coalesced global reads, column-major
// LDS store (transpose-on-write). 14 sorts over 4 waves. Attention scores via
// MFMA f16 (K=6 padded to 32): wave = (d, o-half of 96), 192 MFMAs/wave,
// exp+den/num accumulated in-register on C-fragments. Blocks 512..575: w1t.
// ---------------------------------------------------------------------------
__global__ __launch_bounds__(256) void fused_kernel(
    const float* __restrict__ x, const float* __restrict__ x_date,
    const float* __restrict__ y_date, const float* __restrict__ w1,
    float* __restrict__ V, float* __restrict__ ymean,
    float* __restrict__ bnp, unsigned short* __restrict__ errb,
    unsigned short* __restrict__ w1t) {
  __shared__ float lds[LDSF];
  int orig = blockIdx.x;
  int tid = threadIdx.x, lane = tid & 63, wv = tid >> 6;

  if (orig >= 512) {
    // ---- w1 -> w1t bf16, 64x64 tile (independent of main path) ----
    float* tw = lds;                           // 64*68 = 4352 floats
    int id = orig - 512;                       // 0..63
    int l0 = (id & 7) * 64, m0 = (id >> 3) * 64;
    #pragma unroll
    for (int it = 0; it < 4; ++it) {           // 64 l-rows x 16 float4
      int f = tid + it * 256;
      int row = f >> 4, c4 = f & 15;
      float4 v = ((const float4*)(w1 + (size_t)(l0 + row) * DM + m0))[c4];
      float* p = &tw[row * 68 + c4 * 4];
      p[0] = v.x; p[1] = v.y; p[2] = v.z; p[3] = v.w;
    }
    __syncthreads();
    unsigned int* w1t32 = (unsigned int*)w1t;
    #pragma unroll
    for (int it = 0; it < 8; ++it) {           // 64 m-rows x 32 uints
      int f = tid + it * 256;
      int mr = f >> 5, c = f & 31;
      float a = tw[(c * 2 + 0) * 68 + mr];
      float b = tw[(c * 2 + 1) * 68 + mr];
      unsigned int u = (unsigned int)f2bf(a) | ((unsigned int)f2bf(b) << 16);
      w1t32[(size_t)(m0 + mr) * (DM / 2) + (l0 >> 1) + c] = u;
    }
    return;
  }

  // XCD-aware swizzle: 64 blocks per XCD = 4 b's x 16 d-pairs.
  int xcd = orig & 7, idx = orig >> 3;         // idx 0..63
  int b = (xcd << 2) | (idx >> 4);
  int d0 = (idx & 15) << 1;                    // pair base d

  // ---- coalesced read + transpose-on-write: x_date rows (3 float4) ----
  const float* xs = x_date + (size_t)b * LL * 192 + d0 * 6;
  #pragma unroll
  for (int it = 0; it < 6; ++it) {             // 512 rows x 3 float4
    int f = tid + it * 256;
    int row = f / 3, c4 = f % 3;
    float4 v = ((const float4*)(xs + (size_t)row * 192))[c4];
    int col = c4 * 4;
    lds[XD0 + (col + 0) * CSTR2 + row] = v.x;
    lds[XD0 + (col + 1) * CSTR2 + row] = v.y;
    lds[XD0 + (col + 2) * CSTR2 + row] = v.z;
    lds[XD0 + (col + 3) * CSTR2 + row] = v.w;
  }
  #pragma unroll
  for (int it = 0; it < 2; ++it) {             // 512 rows x float2 (2 d's)
    int row = tid + it * 256;
    float2 v = *(const float2*)(x + (size_t)(b * LL + row) * DD + d0);
    lds[XV0 + row]         = v.x;
    lds[XV0 + CSTR2 + row] = v.y;
  }

  // ---- prefetch y_date column (d = d0 + dl) — only half-0 waves need it ----
  int dl = wv >> 1, half = wv & 1;
  int dme = d0 + dl;
  float2 yr[3][3];
  if (half == 0) {
    #pragma unroll
    for (int j = 0; j < 3; ++j) {
      const float2* yp = (const float2*)(
          y_date + (((size_t)b * OO + (lane + 64 * j)) * DD + dme) * KK);
      yr[j][0] = yp[0]; yr[j][1] = yp[1]; yr[j][2] = yp[2];
    }
  }
  __syncthreads();

  // ---- 14 sorts: 4 rounds x 4 waves.  s<12: x_date col, s>=12: x col ----
  for (int p = 0; p < 4; ++p) {
    int s = p * 4 + wv;
    if (s < 14) {
      const float4* colp = (s < 12)
          ? (const float4*)&lds[XD0 + s * CSTR2 + lane * 8]
          : (const float4*)&lds[XV0 + (s - 12) * CSTR2 + lane * 8];
      float v[8];
      float4 c0 = colp[0], c1 = colp[1];
      v[0]=c0.x; v[1]=c0.y; v[2]=c0.z; v[3]=c0.w;
      v[4]=c1.x; v[5]=c1.y; v[6]=c1.z; v[7]=c1.w;
      sort512(v, lane);
      float e127 = __shfl(v[7], 15);
      float e128 = __shfl(v[0], 16);
      float e255 = __shfl(v[7], 31);
      float e383 = __shfl(v[7], 47);
      float e384 = __shfl(v[0], 48);
      if (lane == 0) {
        float q25 = e127 + 0.75f * (e128 - e127);   // 0.25*(n-1)=127.75
        float q75 = e383 + 0.25f * (e384 - e383);   // 0.75*(n-1)=383.25
        lds[MEDO + s] = e255;                       // torch lower-median
        lds[STDO + s] = q75 - q25 + 1e-6f;
      }
    }
  }
  __syncthreads();

  if (tid < 12) {
    int dloc = tid / 6;
    float a = lds[STDO + 12 + dloc] / lds[STDO + tid];
    lds[SAO + tid] = a;
    lds[SCO + tid] = lds[MEDO + 12 + dloc] - lds[MEDO + tid] * a;
  }
  __syncthreads();

  const float PSC = 0.58912435f;   // (1/sqrt(6)) * log2(e)

  // ---- affine map + err (bf16 to global) + packed Xm rows in regs ----
  float4 packed[2][2];
  #pragma unroll
  for (int dli = 0; dli < 2; ++dli) {
    int cb = dli * 6;
    float a0 = lds[SAO+cb+0], a1 = lds[SAO+cb+1], a2 = lds[SAO+cb+2];
    float a3 = lds[SAO+cb+3], a4 = lds[SAO+cb+4], a5 = lds[SAO+cb+5];
    float c0 = lds[SCO+cb+0], c1 = lds[SCO+cb+1], c2 = lds[SCO+cb+2];
    float c3 = lds[SCO+cb+3], c4 = lds[SCO+cb+4], c5 = lds[SCO+cb+5];
    #pragma unroll
    for (int it = 0; it < 2; ++it) {
      int l = tid + it * 256;
      float m0 = a0 * lds[XD0 + (cb + 0) * CSTR2 + l] + c0;
      float m1 = a1 * lds[XD0 + (cb + 1) * CSTR2 + l] + c1;
      float m2 = a2 * lds[XD0 + (cb + 2) * CSTR2 + l] + c2;
      float m3 = a3 * lds[XD0 + (cb + 3) * CSTR2 + l] + c3;
      float m4 = a4 * lds[XD0 + (cb + 4) * CSTR2 + l] + c4;
      float m5 = a5 * lds[XD0 + (cb + 5) * CSTR2 + l] + c5;
      float xvv = lds[XV0 + dli * CSTR2 + l];
      errb[(size_t)((b << 5) | (d0 + dli)) * LL + l] =
          f2bf(xvv - (m0 + m1 + m2 + m3 + m4 + m5) * (1.0f / 6.0f));
      packed[it][dli].x = asF(__builtin_amdgcn_cvt_pkrtz(m0 * PSC, m1 * PSC));
      packed[it][dli].y = asF(__builtin_amdgcn_cvt_pkrtz(m2 * PSC, m3 * PSC));
      packed[it][dli].z = asF(__builtin_amdgcn_cvt_pkrtz(m4 * PSC, m5 * PSC));
      packed[it][dli].w = 0.0f;                       // k=6..7 zero pad
    }
  }
  __syncthreads();   // all XD reads done; safe to overlay with XMP/YMP

  // ---- write Xm pack (f16, K padded) + Ym pack + ymean (half-0 waves) ----
  #pragma unroll
  for (int it = 0; it < 2; ++it) {
    int l = tid + it * 256;
    *(float4*)&lds[XMP + (0 * 512 + l) * 4] = packed[it][0];
    *(float4*)&lds[XMP + (1 * 512 + l) * 4] = packed[it][1];
  }
  if (half == 0) {
    float askw[6], cskw[6];
    #pragma unroll
    for (int k = 0; k < 6; ++k) {
      askw[k] = lds[SAO + dl * 6 + k];
      cskw[k] = lds[SCO + dl * 6 + k];
    }
    #pragma unroll
    for (int j = 0; j < 3; ++j) {
      int o = lane + 64 * j;
      float q0 = askw[0] * yr[j][0].x + cskw[0];
      float q1 = askw[1] * yr[j][0].y + cskw[1];
      float q2 = askw[2] * yr[j][1].x + cskw[2];
      float q3 = askw[3] * yr[j][1].y + cskw[3];
      float q4 = askw[4] * yr[j][2].x + cskw[4];
      float q5 = askw[5] * yr[j][2].y + cskw[5];
      ymean[(size_t)((b << 5) | dme) * OO + o] =
          (q0 + q1 + q2 + q3 + q4 + q5) * (1.0f / 6.0f);
      float4 yq;
      yq.x = asF(__builtin_amdgcn_cvt_pkrtz(q0, q1));
      yq.y = asF(__builtin_amdgcn_cvt_pkrtz(q2, q3));
      yq.z = asF(__builtin_amdgcn_cvt_pkrtz(q4, q5));
      yq.w = 0.0f;
      *(float4*)&lds[YMP + (dl * 192 + o) * 4] = yq;
    }
  }
  __syncthreads();

  // ---- attention via MFMA: wave = (dl, o-half). 6 o-tiles x 32 l-tiles ----
  {
    int l15 = lane & 15, kg = lane >> 4;
    uint4 zero4 = make_uint4(0u, 0u, 0u, 0u);

    UH8F bf[6];
    #pragma unroll
    for (int ot = 0; ot < 6; ++ot) {
      int brow = (half * 6 + ot) * 16 + l15;
      uint4 bu = *(const uint4*)&lds[YMP + (dl * 192 + brow) * 4];
      bf[ot].u = (kg == 0) ? bu : zero4;       // k>=8 lanes feed zeros
    }

    float den[6] = {0.f,0.f,0.f,0.f,0.f,0.f};
    float num[6] = {0.f,0.f,0.f,0.f,0.f,0.f};

    for (int lt = 0; lt < 32; ++lt) {
      UH8F af;
      uint4 au = *(const uint4*)&lds[XMP + (dl * 512 + lt * 16 + l15) * 4];
      af.u = (kg == 0) ? au : zero4;
      int rbase = lt * 16 + kg * 4;
      float xv0 = lds[XV0 + dl * CSTR2 + rbase + 0];
      float xv1 = lds[XV0 + dl * CSTR2 + rbase + 1];
      float xv2 = lds[XV0 + dl * CSTR2 + rbase + 2];
      float xv3 = lds[XV0 + dl * CSTR2 + rbase + 3];
      #pragma unroll
      for (int ot = 0; ot < 6; ++ot) {
        f4 c = __builtin_amdgcn_mfma_f32_16x16x32_f16(
            af.h, bf[ot].h, (f4){0.f, 0.f, 0.f, 0.f}, 0, 0, 0);
        float e0 = exp2f(c[0]), e1 = exp2f(c[1]);
        float e2 = exp2f(c[2]), e3 = exp2f(c[3]);
        den[ot] += (e0 + e1) + (e2 + e3);
        num[ot] += (e0 * xv0 + e1 * xv1) + (e2 * xv2 + e3 * xv3);
      }
    }

    // reduce across the 4 k-groups (rows) -> full column sums in all lanes
    #pragma unroll
    for (int ot = 0; ot < 6; ++ot) {
      den[ot] += __shfl_xor(den[ot], 16);
      den[ot] += __shfl_xor(den[ot], 32);
      num[ot] += __shfl_xor(num[ot], 16);
      num[ot] += __shfl_xor(num[ot], 32);
    }

    float s1 = 0.f, s2 = 0.f;
    if (lane < 16) {
      #pragma unroll
      for (int ot = 0; ot < 6; ++ot) {
        float vv = num[ot] / den[ot];
        V[(size_t)((b << 5) | dme) * OO + half * 96 + ot * 16 + lane] = vv;
        s1 += vv; s2 += vv * vv;
      }
    }
    s1 += __shfl_xor(s1, 1); s1 += __shfl_xor(s1, 2);
    s1 += __shfl_xor(s1, 4); s1 += __shfl_xor(s1, 8);
    s2 += __shfl_xor(s2, 1); s2 += __shfl_xor(s2, 2);
    s2 += __shfl_xor(s2, 4); s2 += __shfl_xor(s2, 8);
    if (lane == 0) { lds[BNR + wv] = s1; lds[BNR + 8 + wv] = s2; }
  }
  __syncthreads();

  if (tid == 0) {
    float S0  = lds[BNR + 0] + lds[BNR + 1];
    float S20 = lds[BNR + 8 + 0] + lds[BNR + 8 + 1];
    float S1  = lds[BNR + 2] + lds[BNR + 3];
    float S21 = lds[BNR + 8 + 2] + lds[BNR + 8 + 3];
    bnp[(d0 << 5) | b]                = S0;    // no atomics: per-(d,b)
    bnp[1024 + ((d0 << 5) | b)]       = S20;
    bnp[((d0 + 1) << 5) | b]          = S1;
    bnp[1024 + (((d0 + 1) << 5) | b)] = S21;
  }
}

// ---------------------------------------------------------------------------
// K2 gate: 256 blocks = (b, m-slice of 64). NO redundancy: each block computes
// h[m] = err_b,d . w1[:,m] for its 64 m's x all 32 d via MFMA, applies gelu
// and the w2 contraction, and writes a 32-float partial logit per (b,slice).
// ---------------------------------------------------------------------------
__global__ __launch_bounds__(256) void gate_kernel(
    const unsigned short* __restrict__ errb, const unsigned short* __restrict__ w1t,
    const float* __restrict__ b1, const float* __restrict__ w2,
    float* __restrict__ gatep) {
  __shared__ float part[4][32];
  int orig = blockIdx.x;
  int xcd = orig & 7, idx = orig >> 3;         // idx 0..31
  int b = (xcd << 2) | (idx >> 3);
  int s = idx & 7;                             // m-slice
  int tid = threadIdx.x, lane = tid & 63, wv = tid >> 6;
  int m16 = lane & 15, quad = lane >> 4;
  int mw = s * 64 + wv * 16;                   // this wave's 16 m's
  int r0 = b * 32;

  float b1v = b1[mw + m16];
  float2 w2p = ((const float2*)w2)[mw + m16];
  float w2d = w2p.x - w2p.y;

  f4 acc[2];
  acc[0] = (f4){0.f, 0.f, 0.f, 0.f};
  acc[1] = (f4){0.f, 0.f, 0.f, 0.f};

  const unsigned short* ea = errb + (size_t)(r0 + m16) * DM + quad * 8;
  const unsigned short* eb = ea + 16 * DM;
  const unsigned short* wb = w1t + (size_t)(mw + m16) * DM + quad * 8;

  #pragma unroll
  for (int ks = 0; ks < DM; ks += 32) {
    U16x8 ua0, ua1, ub;
    ua0.u = *(const uint4*)(ea + ks);
    ua1.u = *(const uint4*)(eb + ks);
    ub.u  = *(const uint4*)(wb + ks);
    acc[0] = __builtin_amdgcn_mfma_f32_16x16x32_bf16(ua0.h, ub.h, acc[0], 0, 0, 0);
    acc[1] = __builtin_amdgcn_mfma_f32_16x16x32_bf16(ua1.h, ub.h, acc[1], 0, 0, 0);
  }

  float rsum[2][4];
  #pragma unroll
  for (int rt = 0; rt < 2; ++rt) {
    #pragma unroll
    for (int r = 0; r < 4; ++r) {
      float h = acc[rt][r] + b1v;
      float gg = 0.5f * h * (1.0f + erff(h * 0.70710678f));
      rsum[rt][r] = gg * w2d;
    }
  }
  #pragma unroll
  for (int rt = 0; rt < 2; ++rt) {
    #pragma unroll
    for (int r = 0; r < 4; ++r) {
      rsum[rt][r] += __shfl_xor(rsum[rt][r], 1);
      rsum[rt][r] += __shfl_xor(rsum[rt][r], 2);
      rsum[rt][r] += __shfl_xor(rsum[rt][r], 4);
      rsum[rt][r] += __shfl_xor(rsum[rt][r], 8);
    }
  }
  if (m16 == 0) {
    #pragma unroll
    for (int rt = 0; rt < 2; ++rt)
      #pragma unroll
      for (int r = 0; r < 4; ++r)
        part[wv][rt * 16 + quad * 4 + r] = rsum[rt][r];
  }
  __syncthreads();

  if (tid < 32) {
    float p = part[0][tid] + part[1][tid] + part[2][tid] + part[3][tid];
    gatep[(size_t)(((b << 3) | s) << 5) | tid] = p;   // partial for (b, d=tid)
  }
}

// ---------------------------------------------------------------------------
// K3 tail: 256 blocks = (b, o-eighth of 24). Pure elementwise: sum the 8
// gate partials, bn constants from bnp, gated fusion, coalesced out writes.
// ---------------------------------------------------------------------------
__global__ __launch_bounds__(256) void tail_kernel(
    const float* __restrict__ gatep, const float* __restrict__ b2,
    const float* __restrict__ V, const float* __restrict__ ymean,
    const float* __restrict__ bnp,
    const float* __restrict__ gamma, const float* __restrict__ beta,
    float* __restrict__ out) {
  __shared__ float vsh[32 * 28], ysh[32 * 28];
  __shared__ float gsh[32], ssh[32], osh[32];
  int g = blockIdx.x, tid = threadIdx.x;
  int xcd = g & 7, idx = g >> 3;
  int b = (xcd << 2) | (idx >> 3);
  int o0 = (idx & 7) * 24;

  if (tid < 192) {
    int dd = tid / 6, c4 = tid % 6;
    size_t goff = (size_t)(b * DD + dd) * OO + o0;
    float4 v = ((const float4*)(V + goff))[c4];
    float4 y = ((const float4*)(ymean + goff))[c4];
    *(float4*)&vsh[dd * 28 + c4 * 4] = v;
    *(float4*)&ysh[dd * 28 + c4 * 4] = y;
  }

  if (tid < 32) {
    float ld = b2[0] - b2[1];
    #pragma unroll
    for (int s = 0; s < 8; ++s)
      ld += gatep[(size_t)(((b << 3) | s) << 5) | tid];
    gsh[tid] = 1.0f / (1.0f + expf(-ld));      // gate w0 for (b, d=tid)
    float S = 0.f, S2 = 0.f;
    const float* pd = bnp + (tid << 5);
    #pragma unroll 8
    for (int bb = 0; bb < 32; ++bb) { S += pd[bb]; S2 += pd[1024 + bb]; }
    const float inv = 1.0f / (BB * OO);
    float mu = S * inv;
    float var = S2 * inv - mu * mu;
    float gg = gamma[tid] * rsqrtf(var + 1e-5f);
    ssh[tid] = gg;
    osh[tid] = beta[tid] - mu * gg;
  }
  __syncthreads();

  if (tid < 192) {
    int op = tid >> 3, c4 = tid & 7;
    float4 r;
    #pragma unroll
    for (int j = 0; j < 4; ++j) {
      int dd = c4 * 4 + j;
      float v  = vsh[dd * 28 + op];
      float ym = ysh[dd * 28 + op];
      float gg = gsh[dd];
      float y  = v * ssh[dd] + osh[dd];
      ((float*)&r)[j] = ym * gg + y * (1.0f - gg);
    }
    ((float4*)(out + (size_t)(b * OO + o0 + op) * DD))[c4] = r;
  }
}

// ---------------------------------------------------------------------------
extern "C" void kernel_launch(void* const* d_in, const int* in_sizes, int n_in,
                              void* d_out, int out_size, void* d_ws, size_t ws_size,
                              hipStream_t stream) {
  const float* x      = (const float*)d_in[0];
  const float* x_date = (const float*)d_in[1];
  const float* y_date = (const float*)d_in[2];
  const float* w1     = (const float*)d_in[3];
  const float* b1     = (const float*)d_in[4];
  const float* w2     = (const float*)d_in[5];
  const float* b2     = (const float*)d_in[6];
  const float* gamma  = (const float*)d_in[7];
  const float* beta   = (const float*)d_in[8];
  float* out = (float*)d_out;

  float* ws    = (float*)d_ws;
  float* V     = ws;                             // [0, 196608)   (B,D,O)
  float* ymean = ws + 196608;                    // [196608, 393216)
  float* bnp   = ws + 393216;                    // [393216, 395264)
  unsigned short* errb = (unsigned short*)(ws + 395264);   // [395264, 657408) 1024x512 bf16
  unsigned short* w1t  = (unsigned short*)(ws + 657408);   // [657408, 788480) 512x512 bf16 (m,l)
  float* gatep = ws + 788480;                    // [788480, 796672) 32b x 8s x 32d

  fused_kernel<<<576, 256, 0, stream>>>(x, x_date, y_date, w1,
                                        V, ymean, bnp, errb, w1t);
  gate_kernel<<<256, 256, 0, stream>>>(errb, w1t, b1, w2, gatep);
  tail_kernel<<<256, 256, 0, stream>>>(gatep, b2, V, ymean, bnp,
                                       gamma, beta, out);
}

// Round 11
// 138.298 us; speedup vs baseline: 1.2408x; 1.0307x over previous
//
#include <hip/hip_runtime.h>
#include <math.h>

#define BB 32
#define LL 512
#define DD 32
#define KK 6
#define OO 192
#define DM 512

typedef __fp16 h2 __attribute__((ext_vector_type(2)));
typedef __fp16 h8 __attribute__((ext_vector_type(8)));
union F2H { float f; h2 h; };
__device__ __forceinline__ float asF(h2 h) { F2H u; u.h = h; return u.f; }
__device__ __forceinline__ h2 asH(float f) { F2H u; u.f = f; return u.h; }

typedef short bf16x8 __attribute__((ext_vector_type(8)));
typedef float f4 __attribute__((ext_vector_type(4)));
union U16x8 { uint4 u; bf16x8 h; };
union UH8F { uint4 u; h8 h; };

__device__ __forceinline__ unsigned short f2bf(float x) {   // RNE f32->bf16
  unsigned int u = __float_as_uint(x);
  u = (u + 0x7FFF + ((u >> 16) & 1)) >> 16;
  return (unsigned short)u;
}

#define MOVDPP(x, ctrl) \
  __int_as_float(__builtin_amdgcn_mov_dpp(__float_as_int(x), ctrl, 0xf, 0xf, true))

// LDS layout (float slots), d-pair blocks, COLUMN-MAJOR x/x_date storage.
// CSTR2=524: 16B-aligned columns (sort gather = conflict-free b128),
// and 4*524 % 32 == 16 -> transpose-writes ~2-way (free).
#define CSTR2 524
#define XD0   0                  // 12 cols x 524           (6288)
#define XV0   6288               // 2 cols x 524            (1048) -> 7336
#define MEDO  7336               // 14
#define STDO  7350               // 14
#define SAO   7364               // 12
#define SCO   7376               // 12
#define BNR   7388               // 16 bn wave partials
// overlays of the dead XD region after the map phase:
#define XMP   0                  // Xm pack: [2 d][512 l][8 f16] = 4096 floats
#define YMP   4096               // Ym pack: [2 d][192 o][8 f16] = 1536 -> 5632 < 6288
#define DEN   7404               // [8 wv][96]  (768)
#define NUM   8172               // [8 wv][96]  (768)
#define LDSF  8940               // 35.8 KB (2 blocks/CU with headroom)

// ---------------------------------------------------------------------------
// In-register bitonic sort of 512 floats across one wave (8 elems/lane).
// ---------------------------------------------------------------------------
__device__ __forceinline__ void sort512(float v[8], int lane) {
  #pragma unroll
  for (int k = 2; k <= 512; k <<= 1) {
    #pragma unroll
    for (int j = k >> 1; j > 0; j >>= 1) {
      if (j >= 8) {
        int jj = j >> 3;
        bool lower = (lane & jj) == 0;
        bool asc = ((lane << 3) & k) == 0;
        bool keepmin = (asc == lower);
        #pragma unroll
        for (int r = 0; r < 8; ++r) {
          float o;
          if (jj == 1)      o = MOVDPP(v[r], 0xB1);   // quad_perm [1,0,3,2]
          else if (jj == 2) o = MOVDPP(v[r], 0x4E);   // quad_perm [2,3,0,1]
          else if (jj == 8) o = MOVDPP(v[r], 0x128);  // row_ror:8 == xor8
          else              o = __shfl_xor(v[r], jj);
          v[r] = keepmin ? fminf(v[r], o) : fmaxf(v[r], o);
        }
      } else {
        #pragma unroll
        for (int r = 0; r < 8; ++r) {
          if ((r & j) == 0) {
            int r2 = r | j;
            bool asc = (((lane << 3) | r) & k) == 0;
            float a = v[r], b = v[r2];
            float lo = fminf(a, b), hi = fmaxf(a, b);
            v[r]  = asc ? lo : hi;
            v[r2] = asc ? hi : lo;
          }
        }
      }
    }
  }
}

// ---------------------------------------------------------------------------
// K1 fused: blocks 0..511 = (b, d-pair), 512 THREADS (8 waves -> 4 waves/SIMD
// at 2 blocks/CU; R10 was 2/SIMD and latency-bound at 17% occupancy).
// Sorts: 2 rounds x 8 waves. Attention: wave = (d, o-half, l-half), MFMA f16,
// LDS den/num combine across l-halves. Blocks 512..575: w1 -> w1t bf16.
// ---------------------------------------------------------------------------
__global__ __launch_bounds__(512, 4) void fused_kernel(
    const float* __restrict__ x, const float* __restrict__ x_date,
    const float* __restrict__ y_date, const float* __restrict__ w1,
    float* __restrict__ V, float* __restrict__ ymean,
    float* __restrict__ bnp, unsigned short* __restrict__ errb,
    unsigned short* __restrict__ w1t) {
  __shared__ float lds[LDSF];
  int orig = blockIdx.x;
  int tid = threadIdx.x, lane = tid & 63, wv = tid >> 6;

  if (orig >= 512) {
    // ---- w1 -> w1t bf16, 64x64 tile (independent of main path) ----
    float* tw = lds;                           // 64*68 = 4352 floats
    int id = orig - 512;                       // 0..63
    int l0 = (id & 7) * 64, m0 = (id >> 3) * 64;
    #pragma unroll
    for (int it = 0; it < 2; ++it) {           // 64 l-rows x 16 float4
      int f = tid + it * 512;
      int row = f >> 4, c4 = f & 15;
      float4 v = ((const float4*)(w1 + (size_t)(l0 + row) * DM + m0))[c4];
      float* p = &tw[row * 68 + c4 * 4];
      p[0] = v.x; p[1] = v.y; p[2] = v.z; p[3] = v.w;
    }
    __syncthreads();
    unsigned int* w1t32 = (unsigned int*)w1t;
    #pragma unroll
    for (int it = 0; it < 4; ++it) {           // 64 m-rows x 32 uints
      int f = tid + it * 512;
      int mr = f >> 5, c = f & 31;
      float a = tw[(c * 2 + 0) * 68 + mr];
      float b = tw[(c * 2 + 1) * 68 + mr];
      unsigned int u = (unsigned int)f2bf(a) | ((unsigned int)f2bf(b) << 16);
      w1t32[(size_t)(m0 + mr) * (DM / 2) + (l0 >> 1) + c] = u;
    }
    return;
  }

  // XCD-aware swizzle: 64 blocks per XCD = 4 b's x 16 d-pairs.
  int xcd = orig & 7, idx = orig >> 3;         // idx 0..63
  int b = (xcd << 2) | (idx >> 4);
  int d0 = (idx & 15) << 1;                    // pair base d

  // ---- coalesced read + transpose-on-write: x_date rows (3 float4) ----
  const float* xs = x_date + (size_t)b * LL * 192 + d0 * 6;
  #pragma unroll
  for (int it = 0; it < 3; ++it) {             // 512 rows x 3 float4
    int f = tid + it * 512;
    int row = f / 3, c4 = f % 3;
    float4 v = ((const float4*)(xs + (size_t)row * 192))[c4];
    int col = c4 * 4;
    lds[XD0 + (col + 0) * CSTR2 + row] = v.x;
    lds[XD0 + (col + 1) * CSTR2 + row] = v.y;
    lds[XD0 + (col + 2) * CSTR2 + row] = v.z;
    lds[XD0 + (col + 3) * CSTR2 + row] = v.w;
  }
  {                                            // 512 rows x float2 (2 d's)
    int row = tid;
    float2 v = *(const float2*)(x + (size_t)(b * LL + row) * DD + d0);
    lds[XV0 + row]         = v.x;
    lds[XV0 + CSTR2 + row] = v.y;
  }

  // ---- prefetch y_date column: one wave per d (wv 0 -> d0, wv 4 -> d0+1) ----
  float2 yr[3][3];
  if ((wv & 3) == 0) {
    int dme = d0 + (wv >> 2);
    #pragma unroll
    for (int j = 0; j < 3; ++j) {
      const float2* yp = (const float2*)(
          y_date + (((size_t)b * OO + (lane + 64 * j)) * DD + dme) * KK);
      yr[j][0] = yp[0]; yr[j][1] = yp[1]; yr[j][2] = yp[2];
    }
  }
  __syncthreads();

  // ---- 14 sorts: 2 rounds x 8 waves.  s<12: x_date col, s>=12: x col ----
  for (int p = 0; p < 2; ++p) {
    int s = p * 8 + wv;
    if (s < 14) {
      const float4* colp = (s < 12)
          ? (const float4*)&lds[XD0 + s * CSTR2 + lane * 8]
          : (const float4*)&lds[XV0 + (s - 12) * CSTR2 + lane * 8];
      float v[8];
      float4 c0 = colp[0], c1 = colp[1];
      v[0]=c0.x; v[1]=c0.y; v[2]=c0.z; v[3]=c0.w;
      v[4]=c1.x; v[5]=c1.y; v[6]=c1.z; v[7]=c1.w;
      sort512(v, lane);
      float e127 = __shfl(v[7], 15);
      float e128 = __shfl(v[0], 16);
      float e255 = __shfl(v[7], 31);
      float e383 = __shfl(v[7], 47);
      float e384 = __shfl(v[0], 48);
      if (lane == 0) {
        float q25 = e127 + 0.75f * (e128 - e127);   // 0.25*(n-1)=127.75
        float q75 = e383 + 0.25f * (e384 - e383);   // 0.75*(n-1)=383.25
        lds[MEDO + s] = e255;                       // torch lower-median
        lds[STDO + s] = q75 - q25 + 1e-6f;
      }
    }
  }
  __syncthreads();

  if (tid < 12) {
    int dloc = tid / 6;
    float a = lds[STDO + 12 + dloc] / lds[STDO + tid];
    lds[SAO + tid] = a;
    lds[SCO + tid] = lds[MEDO + 12 + dloc] - lds[MEDO + tid] * a;
  }
  __syncthreads();

  const float PSC = 0.58912435f;   // (1/sqrt(6)) * log2(e)

  // ---- affine map + err (bf16 to global) + packed Xm rows in regs ----
  float4 packed[2];
  {
    int l = tid;
    #pragma unroll
    for (int dli = 0; dli < 2; ++dli) {
      int cb = dli * 6;
      float m0 = lds[SAO+cb+0] * lds[XD0 + (cb + 0) * CSTR2 + l] + lds[SCO+cb+0];
      float m1 = lds[SAO+cb+1] * lds[XD0 + (cb + 1) * CSTR2 + l] + lds[SCO+cb+1];
      float m2 = lds[SAO+cb+2] * lds[XD0 + (cb + 2) * CSTR2 + l] + lds[SCO+cb+2];
      float m3 = lds[SAO+cb+3] * lds[XD0 + (cb + 3) * CSTR2 + l] + lds[SCO+cb+3];
      float m4 = lds[SAO+cb+4] * lds[XD0 + (cb + 4) * CSTR2 + l] + lds[SCO+cb+4];
      float m5 = lds[SAO+cb+5] * lds[XD0 + (cb + 5) * CSTR2 + l] + lds[SCO+cb+5];
      float xvv = lds[XV0 + dli * CSTR2 + l];
      errb[(size_t)((b << 5) | (d0 + dli)) * LL + l] =
          f2bf(xvv - (m0 + m1 + m2 + m3 + m4 + m5) * (1.0f / 6.0f));
      packed[dli].x = asF(__builtin_amdgcn_cvt_pkrtz(m0 * PSC, m1 * PSC));
      packed[dli].y = asF(__builtin_amdgcn_cvt_pkrtz(m2 * PSC, m3 * PSC));
      packed[dli].z = asF(__builtin_amdgcn_cvt_pkrtz(m4 * PSC, m5 * PSC));
      packed[dli].w = 0.0f;                         // k=6..7 zero pad
    }
  }
  __syncthreads();   // all XD reads done; safe to overlay with XMP/YMP

  // ---- write Xm pack + Ym pack + ymean ----
  *(float4*)&lds[XMP + (0 * 512 + tid) * 4] = packed[0];
  *(float4*)&lds[XMP + (1 * 512 + tid) * 4] = packed[1];
  if ((wv & 3) == 0) {
    int dl = wv >> 2, dme = d0 + dl;
    float askw[6], cskw[6];
    #pragma unroll
    for (int k = 0; k < 6; ++k) {
      askw[k] = lds[SAO + dl * 6 + k];
      cskw[k] = lds[SCO + dl * 6 + k];
    }
    #pragma unroll
    for (int j = 0; j < 3; ++j) {
      int o = lane + 64 * j;
      float q0 = askw[0] * yr[j][0].x + cskw[0];
      float q1 = askw[1] * yr[j][0].y + cskw[1];
      float q2 = askw[2] * yr[j][1].x + cskw[2];
      float q3 = askw[3] * yr[j][1].y + cskw[3];
      float q4 = askw[4] * yr[j][2].x + cskw[4];
      float q5 = askw[5] * yr[j][2].y + cskw[5];
      ymean[(size_t)((b << 5) | dme) * OO + o] =
          (q0 + q1 + q2 + q3 + q4 + q5) * (1.0f / 6.0f);
      float4 yq;
      yq.x = asF(__builtin_amdgcn_cvt_pkrtz(q0, q1));
      yq.y = asF(__builtin_amdgcn_cvt_pkrtz(q2, q3));
      yq.z = asF(__builtin_amdgcn_cvt_pkrtz(q4, q5));
      yq.w = 0.0f;
      *(float4*)&lds[YMP + (dl * 192 + o) * 4] = yq;
    }
  }
  __syncthreads();

  // ---- attention via MFMA: wave = (dl, o-half, l-half). 6 ot x 16 lt ----
  {
    int adl = wv >> 2, oh = (wv >> 1) & 1, lh = wv & 1;
    int l15 = lane & 15, kg = lane >> 4;
    uint4 zero4 = make_uint4(0u, 0u, 0u, 0u);

    UH8F bf[6];
    #pragma unroll
    for (int ot = 0; ot < 6; ++ot) {
      int brow = (oh * 6 + ot) * 16 + l15;
      uint4 bu = *(const uint4*)&lds[YMP + (adl * 192 + brow) * 4];
      bf[ot].u = (kg == 0) ? bu : zero4;       // k>=8 lanes feed zeros
    }

    float den[6] = {0.f,0.f,0.f,0.f,0.f,0.f};
    float num[6] = {0.f,0.f,0.f,0.f,0.f,0.f};

    for (int t = 0; t < 16; ++t) {
      int lt = lh * 16 + t;
      UH8F af;
      uint4 au = *(const uint4*)&lds[XMP + (adl * 512 + lt * 16 + l15) * 4];
      af.u = (kg == 0) ? au : zero4;
      int rbase = lt * 16 + kg * 4;
      float xv0 = lds[XV0 + adl * CSTR2 + rbase + 0];
      float xv1 = lds[XV0 + adl * CSTR2 + rbase + 1];
      float xv2 = lds[XV0 + adl * CSTR2 + rbase + 2];
      float xv3 = lds[XV0 + adl * CSTR2 + rbase + 3];
      #pragma unroll
      for (int ot = 0; ot < 6; ++ot) {
        f4 c = __builtin_amdgcn_mfma_f32_16x16x32_f16(
            af.h, bf[ot].h, (f4){0.f, 0.f, 0.f, 0.f}, 0, 0, 0);
        float e0 = exp2f(c[0]), e1 = exp2f(c[1]);
        float e2 = exp2f(c[2]), e3 = exp2f(c[3]);
        den[ot] += (e0 + e1) + (e2 + e3);
        num[ot] += (e0 * xv0 + e1 * xv1) + (e2 * xv2 + e3 * xv3);
      }
    }

    // reduce across the 4 k-groups (rows) -> column sums for this l-half
    #pragma unroll
    for (int ot = 0; ot < 6; ++ot) {
      den[ot] += __shfl_xor(den[ot], 16);
      den[ot] += __shfl_xor(den[ot], 32);
      num[ot] += __shfl_xor(num[ot], 16);
      num[ot] += __shfl_xor(num[ot], 32);
    }
    if (lane < 16) {
      #pragma unroll
      for (int ot = 0; ot < 6; ++ot) {
        lds[DEN + wv * 96 + ot * 16 + lane] = den[ot];
        lds[NUM + wv * 96 + ot * 16 + lane] = num[ot];
      }
    }
  }
  __syncthreads();

  // ---- combine l-halves, V write, bn partials ----
  float s1 = 0.f, s2 = 0.f;
  if (tid < 384) {
    int dl2 = tid / 192, o = tid % 192;
    int oh2 = o / 96, r96 = o % 96;            // r96 == ot*16 + l16
    int wv0 = dl2 * 4 + oh2 * 2;
    float dsum = lds[DEN + wv0 * 96 + r96] + lds[DEN + (wv0 + 1) * 96 + r96];
    float nsum = lds[NUM + wv0 * 96 + r96] + lds[NUM + (wv0 + 1) * 96 + r96];
    float vv = nsum / dsum;
    V[(size_t)((b << 5) | (d0 + dl2)) * OO + o] = vv;
    s1 = vv; s2 = vv * vv;
  }
  #pragma unroll
  for (int off = 32; off > 0; off >>= 1) {
    s1 += __shfl_down(s1, off);
    s2 += __shfl_down(s2, off);
  }
  if (lane == 0) { lds[BNR + wv] = s1; lds[BNR + 8 + wv] = s2; }
  __syncthreads();
  if (tid == 0) {
    float S0  = lds[BNR + 0] + lds[BNR + 1] + lds[BNR + 2];
    float S20 = lds[BNR + 8] + lds[BNR + 9] + lds[BNR + 10];
    float S1  = lds[BNR + 3] + lds[BNR + 4] + lds[BNR + 5];
    float S21 = lds[BNR + 11] + lds[BNR + 12] + lds[BNR + 13];
    bnp[(d0 << 5) | b]                = S0;    // no atomics: per-(d,b)
    bnp[1024 + ((d0 << 5) | b)]       = S20;
    bnp[((d0 + 1) << 5) | b]          = S1;
    bnp[1024 + (((d0 + 1) << 5) | b)] = S21;
  }
}

// ---------------------------------------------------------------------------
// K2 gate: 256 blocks = (b, m-slice of 64). NO redundancy: each block computes
// h[m] = err_b,d . w1[:,m] for its 64 m's x all 32 d via MFMA, applies gelu
// and the w2 contraction, and writes a 32-float partial logit per (b,slice).
// ---------------------------------------------------------------------------
__global__ __launch_bounds__(256) void gate_kernel(
    const unsigned short* __restrict__ errb, const unsigned short* __restrict__ w1t,
    const float* __restrict__ b1, const float* __restrict__ w2,
    float* __restrict__ gatep) {
  __shared__ float part[4][32];
  int orig = blockIdx.x;
  int xcd = orig & 7, idx = orig >> 3;         // idx 0..31
  int b = (xcd << 2) | (idx >> 3);
  int s = idx & 7;                             // m-slice
  int tid = threadIdx.x, lane = tid & 63, wv = tid >> 6;
  int m16 = lane & 15, quad = lane >> 4;
  int mw = s * 64 + wv * 16;                   // this wave's 16 m's
  int r0 = b * 32;

  float b1v = b1[mw + m16];
  float2 w2p = ((const float2*)w2)[mw + m16];
  float w2d = w2p.x - w2p.y;

  f4 acc[2];
  acc[0] = (f4){0.f, 0.f, 0.f, 0.f};
  acc[1] = (f4){0.f, 0.f, 0.f, 0.f};

  const unsigned short* ea = errb + (size_t)(r0 + m16) * DM + quad * 8;
  const unsigned short* eb = ea + 16 * DM;
  const unsigned short* wb = w1t + (size_t)(mw + m16) * DM + quad * 8;

  #pragma unroll
  for (int ks = 0; ks < DM; ks += 32) {
    U16x8 ua0, ua1, ub;
    ua0.u = *(const uint4*)(ea + ks);
    ua1.u = *(const uint4*)(eb + ks);
    ub.u  = *(const uint4*)(wb + ks);
    acc[0] = __builtin_amdgcn_mfma_f32_16x16x32_bf16(ua0.h, ub.h, acc[0], 0, 0, 0);
    acc[1] = __builtin_amdgcn_mfma_f32_16x16x32_bf16(ua1.h, ub.h, acc[1], 0, 0, 0);
  }

  float rsum[2][4];
  #pragma unroll
  for (int rt = 0; rt < 2; ++rt) {
    #pragma unroll
    for (int r = 0; r < 4; ++r) {
      float h = acc[rt][r] + b1v;
      float gg = 0.5f * h * (1.0f + erff(h * 0.70710678f));
      rsum[rt][r] = gg * w2d;
    }
  }
  #pragma unroll
  for (int rt = 0; rt < 2; ++rt) {
    #pragma unroll
    for (int r = 0; r < 4; ++r) {
      rsum[rt][r] += __shfl_xor(rsum[rt][r], 1);
      rsum[rt][r] += __shfl_xor(rsum[rt][r], 2);
      rsum[rt][r] += __shfl_xor(rsum[rt][r], 4);
      rsum[rt][r] += __shfl_xor(rsum[rt][r], 8);
    }
  }
  if (m16 == 0) {
    #pragma unroll
    for (int rt = 0; rt < 2; ++rt)
      #pragma unroll
      for (int r = 0; r < 4; ++r)
        part[wv][rt * 16 + quad * 4 + r] = rsum[rt][r];
  }
  __syncthreads();

  if (tid < 32) {
    float p = part[0][tid] + part[1][tid] + part[2][tid] + part[3][tid];
    gatep[(size_t)(((b << 3) | s) << 5) | tid] = p;   // partial for (b, d=tid)
  }
}

// ---------------------------------------------------------------------------
// K3 tail: 256 blocks = (b, o-eighth of 24). Pure elementwise: sum the 8
// gate partials, bn constants from bnp, gated fusion, coalesced out writes.
// ---------------------------------------------------------------------------
__global__ __launch_bounds__(256) void tail_kernel(
    const float* __restrict__ gatep, const float* __restrict__ b2,
    const float* __restrict__ V, const float* __restrict__ ymean,
    const float* __restrict__ bnp,
    const float* __restrict__ gamma, const float* __restrict__ beta,
    float* __restrict__ out) {
  __shared__ float vsh[32 * 28], ysh[32 * 28];
  __shared__ float gsh[32], ssh[32], osh[32];
  int g = blockIdx.x, tid = threadIdx.x;
  int xcd = g & 7, idx = g >> 3;
  int b = (xcd << 2) | (idx >> 3);
  int o0 = (idx & 7) * 24;

  if (tid < 192) {
    int dd = tid / 6, c4 = tid % 6;
    size_t goff = (size_t)(b * DD + dd) * OO + o0;
    float4 v = ((const float4*)(V + goff))[c4];
    float4 y = ((const float4*)(ymean + goff))[c4];
    *(float4*)&vsh[dd * 28 + c4 * 4] = v;
    *(float4*)&ysh[dd * 28 + c4 * 4] = y;
  }

  if (tid < 32) {
    float ld = b2[0] - b2[1];
    #pragma unroll
    for (int s = 0; s < 8; ++s)
      ld += gatep[(size_t)(((b << 3) | s) << 5) | tid];
    gsh[tid] = 1.0f / (1.0f + expf(-ld));      // gate w0 for (b, d=tid)
    float S = 0.f, S2 = 0.f;
    const float* pd = bnp + (tid << 5);
    #pragma unroll 8
    for (int bb = 0; bb < 32; ++bb) { S += pd[bb]; S2 += pd[1024 + bb]; }
    const float inv = 1.0f / (BB * OO);
    float mu = S * inv;
    float var = S2 * inv - mu * mu;
    float gg = gamma[tid] * rsqrtf(var + 1e-5f);
    ssh[tid] = gg;
    osh[tid] = beta[tid] - mu * gg;
  }
  __syncthreads();

  if (tid < 192) {
    int op = tid >> 3, c4 = tid & 7;
    float4 r;
    #pragma unroll
    for (int j = 0; j < 4; ++j) {
      int dd = c4 * 4 + j;
      float v  = vsh[dd * 28 + op];
      float ym = ysh[dd * 28 + op];
      float gg = gsh[dd];
      float y  = v * ssh[dd] + osh[dd];
      ((float*)&r)[j] = ym * gg + y * (1.0f - gg);
    }
    ((float4*)(out + (size_t)(b * OO + o0 + op) * DD))[c4] = r;
  }
}

// ---------------------------------------------------------------------------
extern "C" void kernel_launch(void* const* d_in, const int* in_sizes, int n_in,
                              void* d_out, int out_size, void* d_ws, size_t ws_size,
                              hipStream_t stream) {
  const float* x      = (const float*)d_in[0];
  const float* x_date = (const float*)d_in[1];
  const float* y_date = (const float*)d_in[2];
  const float* w1     = (const float*)d_in[3];
  const float* b1     = (const float*)d_in[4];
  const float* w2     = (const float*)d_in[5];
  const float* b2     = (const float*)d_in[6];
  const float* gamma  = (const float*)d_in[7];
  const float* beta   = (const float*)d_in[8];
  float* out = (float*)d_out;

  float* ws    = (float*)d_ws;
  float* V     = ws;                             // [0, 196608)   (B,D,O)
  float* ymean = ws + 196608;                    // [196608, 393216)
  float* bnp   = ws + 393216;                    // [393216, 395264)
  unsigned short* errb = (unsigned short*)(ws + 395264);   // [395264, 657408) 1024x512 bf16
  unsigned short* w1t  = (unsigned short*)(ws + 657408);   // [657408, 788480) 512x512 bf16 (m,l)
  float* gatep = ws + 788480;                    // [788480, 796672) 32b x 8s x 32d

  fused_kernel<<<576, 512, 0, stream>>>(x, x_date, y_date, w1,
                                        V, ymean, bnp, errb, w1t);
  gate_kernel<<<256, 256, 0, stream>>>(errb, w1t, b1, w2, gatep);
  tail_kernel<<<256, 256, 0, stream>>>(gatep, b2, V, ymean, bnp,
                                       gamma, beta, out);
}

// Round 12
// 133.740 us; speedup vs baseline: 1.2831x; 1.0341x over previous
//
#include <hip/hip_runtime.h>
#include <math.h>

#define BB 32
#define LL 512
#define DD 32
#define KK 6
#define OO 192
#define DM 512

typedef __fp16 h2 __attribute__((ext_vector_type(2)));
typedef __fp16 h8 __attribute__((ext_vector_type(8)));
union F2H { float f; h2 h; };
__device__ __forceinline__ float asF(h2 h) { F2H u; u.h = h; return u.f; }
__device__ __forceinline__ h2 asH(float f) { F2H u; u.f = f; return u.h; }

typedef short bf16x8 __attribute__((ext_vector_type(8)));
typedef float f4 __attribute__((ext_vector_type(4)));
union U16x8 { uint4 u; bf16x8 h; };
union UH8F { uint4 u; h8 h; };

__device__ __forceinline__ unsigned short f2bf(float x) {   // RNE f32->bf16
  unsigned int u = __float_as_uint(x);
  u = (u + 0x7FFF + ((u >> 16) & 1)) >> 16;
  return (unsigned short)u;
}

#define MOVDPP(x, ctrl) \
  __int_as_float(__builtin_amdgcn_mov_dpp(__float_as_int(x), ctrl, 0xf, 0xf, true))

// LDS layout (float slots), per-(b,d) blocks, COLUMN-MAJOR storage.
// CSTR2=524: 16B-aligned columns (sort gather = conflict-free b128).
#define CSTR2 524
#define XD0   0                  // 6 cols x 524            (3144)
#define XV0   3144               // 1 col x 524             (524) -> 3668
#define MEDO  3668               // 7
#define STDO  3675               // 7
#define SAO   3682               // 6
#define SCO   3688               // 6
#define BNR   3694               // 16 -> 3710
// overlays of the dead XD region after the map phase:
#define XMP   0                  // Xm pack: [512 l][8 f16] = 2048 floats
#define YMP   2048               // Ym pack: [192 o][8 f16] = 768 -> 2816 < 3144
#define DEN   3712               // [8 wv][96]  (768)
#define NUM   4480               // [8 wv][96]  (768)
#define LDSF  5248               // 21.0 KB -> 4 blocks/CU (grid-limited target)

// ---------------------------------------------------------------------------
// In-register bitonic sort of 512 floats across one wave (8 elems/lane).
// ---------------------------------------------------------------------------
__device__ __forceinline__ void sort512(float v[8], int lane) {
  #pragma unroll
  for (int k = 2; k <= 512; k <<= 1) {
    #pragma unroll
    for (int j = k >> 1; j > 0; j >>= 1) {
      if (j >= 8) {
        int jj = j >> 3;
        bool lower = (lane & jj) == 0;
        bool asc = ((lane << 3) & k) == 0;
        bool keepmin = (asc == lower);
        #pragma unroll
        for (int r = 0; r < 8; ++r) {
          float o;
          if (jj == 1)      o = MOVDPP(v[r], 0xB1);   // quad_perm [1,0,3,2]
          else if (jj == 2) o = MOVDPP(v[r], 0x4E);   // quad_perm [2,3,0,1]
          else if (jj == 8) o = MOVDPP(v[r], 0x128);  // row_ror:8 == xor8
          else              o = __shfl_xor(v[r], jj);
          v[r] = keepmin ? fminf(v[r], o) : fmaxf(v[r], o);
        }
      } else {
        #pragma unroll
        for (int r = 0; r < 8; ++r) {
          if ((r & j) == 0) {
            int r2 = r | j;
            bool asc = (((lane << 3) | r) & k) == 0;
            float a = v[r], b = v[r2];
            float lo = fminf(a, b), hi = fmaxf(a, b);
            v[r]  = asc ? lo : hi;
            v[r2] = asc ? hi : lo;
          }
        }
      }
    }
  }
}

// ---------------------------------------------------------------------------
// K1 fused: blocks 0..1023 = (b, d), 512 threads. 4 blocks/CU x 8 waves =
// 32 waves/CU (2x R11 — R11 was grid-limited at 31% occupancy). One sort per
// wave (7 sorts, 1 round). Attention: wave = (o-half, l-quarter), MFMA f16,
// LDS den/num combine across l-quarters. Blocks 1024..1087: w1 -> w1t bf16.
// ---------------------------------------------------------------------------
__global__ __launch_bounds__(512, 8) void fused_kernel(
    const float* __restrict__ x, const float* __restrict__ x_date,
    const float* __restrict__ y_date, const float* __restrict__ w1,
    float* __restrict__ V, float* __restrict__ ymean,
    float* __restrict__ bnp, unsigned short* __restrict__ errb,
    unsigned short* __restrict__ w1t) {
  __shared__ float lds[LDSF];
  int orig = blockIdx.x;
  int tid = threadIdx.x, lane = tid & 63, wv = tid >> 6;

  if (orig >= 1024) {
    // ---- w1 -> w1t bf16, 64x64 tile (independent of main path) ----
    float* tw = lds;                           // 64*68 = 4352 floats? too big
    // NOTE: LDSF=5248 floats; 64*68=4352 fits.
    int id = orig - 1024;                      // 0..63
    int l0 = (id & 7) * 64, m0 = (id >> 3) * 64;
    #pragma unroll
    for (int it = 0; it < 2; ++it) {           // 64 l-rows x 16 float4
      int f = tid + it * 512;
      int row = f >> 4, c4 = f & 15;
      float4 v = ((const float4*)(w1 + (size_t)(l0 + row) * DM + m0))[c4];
      float* p = &tw[row * 68 + c4 * 4];
      p[0] = v.x; p[1] = v.y; p[2] = v.z; p[3] = v.w;
    }
    __syncthreads();
    unsigned int* w1t32 = (unsigned int*)w1t;
    #pragma unroll
    for (int it = 0; it < 4; ++it) {           // 64 m-rows x 32 uints
      int f = tid + it * 512;
      int mr = f >> 5, c = f & 31;
      float a = tw[(c * 2 + 0) * 68 + mr];
      float b = tw[(c * 2 + 1) * 68 + mr];
      unsigned int u = (unsigned int)f2bf(a) | ((unsigned int)f2bf(b) << 16);
      w1t32[(size_t)(m0 + mr) * (DM / 2) + (l0 >> 1) + c] = u;
    }
    return;
  }

  // XCD-aware swizzle: 128 blocks per XCD = 4 b's x 32 d's.
  int xcd = orig & 7, idx = orig >> 3;         // idx 0..127
  int b = (xcd << 2) | (idx >> 5);
  int d = idx & 31;
  int lbid = (b << 5) | d;

  // ---- staging: x_date rows (3 float2, 24B contiguous) + x (1 float) ----
  const float* xs = x_date + (size_t)b * LL * 192 + d * 6;
  #pragma unroll
  for (int it = 0; it < 3; ++it) {             // 512 rows x 3 float2
    int f = tid + it * 512;
    int row = f / 3, c = f % 3;
    float2 v = ((const float2*)(xs + (size_t)row * 192))[c];
    lds[XD0 + (2 * c + 0) * CSTR2 + row] = v.x;
    lds[XD0 + (2 * c + 1) * CSTR2 + row] = v.y;
  }
  lds[XV0 + tid] = x[(size_t)(b * LL + tid) * DD + d];

  // ---- prefetch y_date: waves 0..2, o = wv*64 + lane ----
  float2 yr0, yr1, yr2;
  if (wv < 3) {
    int o = wv * 64 + lane;
    const float2* yp = (const float2*)(
        y_date + (((size_t)b * OO + o) * DD + d) * KK);
    yr0 = yp[0]; yr1 = yp[1]; yr2 = yp[2];
  }
  __syncthreads();

  // ---- 7 sorts: one per wave (wv<7).  s<6: x_date col, s=6: x col ----
  if (wv < 7) {
    const float4* colp = (wv < 6)
        ? (const float4*)&lds[XD0 + wv * CSTR2 + lane * 8]
        : (const float4*)&lds[XV0 + lane * 8];
    float v[8];
    float4 c0 = colp[0], c1 = colp[1];
    v[0]=c0.x; v[1]=c0.y; v[2]=c0.z; v[3]=c0.w;
    v[4]=c1.x; v[5]=c1.y; v[6]=c1.z; v[7]=c1.w;
    sort512(v, lane);
    float e127 = __shfl(v[7], 15);
    float e128 = __shfl(v[0], 16);
    float e255 = __shfl(v[7], 31);
    float e383 = __shfl(v[7], 47);
    float e384 = __shfl(v[0], 48);
    if (lane == 0) {
      float q25 = e127 + 0.75f * (e128 - e127);   // 0.25*(n-1)=127.75
      float q75 = e383 + 0.25f * (e384 - e383);   // 0.75*(n-1)=383.25
      lds[MEDO + wv] = e255;                      // torch lower-median
      lds[STDO + wv] = q75 - q25 + 1e-6f;
    }
  }
  __syncthreads();

  if (tid < 6) {
    float a = lds[STDO + 6] / lds[STDO + tid];
    lds[SAO + tid] = a;
    lds[SCO + tid] = lds[MEDO + 6] - lds[MEDO + tid] * a;
  }
  __syncthreads();

  const float PSC = 0.58912435f;   // (1/sqrt(6)) * log2(e)

  // ---- affine map + err (bf16 to global) + packed Xm row in regs ----
  float4 packed;
  {
    int l = tid;
    float m0 = lds[SAO+0] * lds[XD0 + 0 * CSTR2 + l] + lds[SCO+0];
    float m1 = lds[SAO+1] * lds[XD0 + 1 * CSTR2 + l] + lds[SCO+1];
    float m2 = lds[SAO+2] * lds[XD0 + 2 * CSTR2 + l] + lds[SCO+2];
    float m3 = lds[SAO+3] * lds[XD0 + 3 * CSTR2 + l] + lds[SCO+3];
    float m4 = lds[SAO+4] * lds[XD0 + 4 * CSTR2 + l] + lds[SCO+4];
    float m5 = lds[SAO+5] * lds[XD0 + 5 * CSTR2 + l] + lds[SCO+5];
    float xvv = lds[XV0 + l];
    errb[(size_t)lbid * LL + l] =
        f2bf(xvv - (m0 + m1 + m2 + m3 + m4 + m5) * (1.0f / 6.0f));
    packed.x = asF(__builtin_amdgcn_cvt_pkrtz(m0 * PSC, m1 * PSC));
    packed.y = asF(__builtin_amdgcn_cvt_pkrtz(m2 * PSC, m3 * PSC));
    packed.z = asF(__builtin_amdgcn_cvt_pkrtz(m4 * PSC, m5 * PSC));
    packed.w = 0.0f;                            // k=6..7 zero pad
  }
  __syncthreads();   // all XD reads done; safe to overlay with XMP/YMP

  *(float4*)&lds[XMP + tid * 4] = packed;
  if (wv < 3) {
    int o = wv * 64 + lane;
    float q0 = lds[SAO+0] * yr0.x + lds[SCO+0];
    float q1 = lds[SAO+1] * yr0.y + lds[SCO+1];
    float q2 = lds[SAO+2] * yr1.x + lds[SCO+2];
    float q3 = lds[SAO+3] * yr1.y + lds[SCO+3];
    float q4 = lds[SAO+4] * yr2.x + lds[SCO+4];
    float q5 = lds[SAO+5] * yr2.y + lds[SCO+5];
    ymean[(size_t)lbid * OO + o] =
        (q0 + q1 + q2 + q3 + q4 + q5) * (1.0f / 6.0f);
    float4 yq;
    yq.x = asF(__builtin_amdgcn_cvt_pkrtz(q0, q1));
    yq.y = asF(__builtin_amdgcn_cvt_pkrtz(q2, q3));
    yq.z = asF(__builtin_amdgcn_cvt_pkrtz(q4, q5));
    yq.w = 0.0f;
    *(float4*)&lds[YMP + o * 4] = yq;
  }
  __syncthreads();

  // ---- attention via MFMA: wave = (o-half, l-quarter). 6 ot x 8 lt ----
  {
    int oh = wv >> 2, lq = wv & 3;
    int l15 = lane & 15, kg = lane >> 4;
    uint4 zero4 = make_uint4(0u, 0u, 0u, 0u);

    UH8F bf[6];
    #pragma unroll
    for (int ot = 0; ot < 6; ++ot) {
      int brow = (oh * 6 + ot) * 16 + l15;
      uint4 bu = *(const uint4*)&lds[YMP + brow * 4];
      bf[ot].u = (kg == 0) ? bu : zero4;       // k>=8 lanes feed zeros
    }

    float den[6] = {0.f,0.f,0.f,0.f,0.f,0.f};
    float num[6] = {0.f,0.f,0.f,0.f,0.f,0.f};

    for (int t = 0; t < 8; ++t) {
      int lt = lq * 8 + t;
      UH8F af;
      uint4 au = *(const uint4*)&lds[XMP + (lt * 16 + l15) * 4];
      af.u = (kg == 0) ? au : zero4;
      int rbase = lt * 16 + kg * 4;
      float xv0 = lds[XV0 + rbase + 0];
      float xv1 = lds[XV0 + rbase + 1];
      float xv2 = lds[XV0 + rbase + 2];
      float xv3 = lds[XV0 + rbase + 3];
      #pragma unroll
      for (int ot = 0; ot < 6; ++ot) {
        f4 c = __builtin_amdgcn_mfma_f32_16x16x32_f16(
            af.h, bf[ot].h, (f4){0.f, 0.f, 0.f, 0.f}, 0, 0, 0);
        float e0 = exp2f(c[0]), e1 = exp2f(c[1]);
        float e2 = exp2f(c[2]), e3 = exp2f(c[3]);
        den[ot] += (e0 + e1) + (e2 + e3);
        num[ot] += (e0 * xv0 + e1 * xv1) + (e2 * xv2 + e3 * xv3);
      }
    }

    // reduce across the 4 k-groups (rows) -> column sums for this l-quarter
    #pragma unroll
    for (int ot = 0; ot < 6; ++ot) {
      den[ot] += __shfl_xor(den[ot], 16);
      den[ot] += __shfl_xor(den[ot], 32);
      num[ot] += __shfl_xor(num[ot], 16);
      num[ot] += __shfl_xor(num[ot], 32);
    }
    if (lane < 16) {
      #pragma unroll
      for (int ot = 0; ot < 6; ++ot) {
        lds[DEN + wv * 96 + ot * 16 + lane] = den[ot];
        lds[NUM + wv * 96 + ot * 16 + lane] = num[ot];
      }
    }
  }
  __syncthreads();

  // ---- combine l-quarters, V write, bn partials ----
  float s1 = 0.f, s2 = 0.f;
  if (tid < OO) {
    int o = tid;
    int oh2 = o / 96, r96 = o % 96;            // r96 == ot*16 + l16
    int w0 = oh2 * 4;
    float dsum = lds[DEN + (w0 + 0) * 96 + r96] + lds[DEN + (w0 + 1) * 96 + r96]
               + lds[DEN + (w0 + 2) * 96 + r96] + lds[DEN + (w0 + 3) * 96 + r96];
    float nsum = lds[NUM + (w0 + 0) * 96 + r96] + lds[NUM + (w0 + 1) * 96 + r96]
               + lds[NUM + (w0 + 2) * 96 + r96] + lds[NUM + (w0 + 3) * 96 + r96];
    float vv = nsum / dsum;
    V[(size_t)lbid * OO + o] = vv;
    s1 = vv; s2 = vv * vv;
  }
  #pragma unroll
  for (int off = 32; off > 0; off >>= 1) {
    s1 += __shfl_down(s1, off);
    s2 += __shfl_down(s2, off);
  }
  if (lane == 0) { lds[BNR + wv] = s1; lds[BNR + 8 + wv] = s2; }
  __syncthreads();
  if (tid == 0) {
    float S  = lds[BNR + 0] + lds[BNR + 1] + lds[BNR + 2];
    float S2 = lds[BNR + 8] + lds[BNR + 9] + lds[BNR + 10];
    bnp[(d << 5) | b]          = S;            // no atomics: per-(d,b)
    bnp[1024 + ((d << 5) | b)] = S2;
  }
}

// ---------------------------------------------------------------------------
// K2 gate: 256 blocks = (b, m-slice of 64). NO redundancy: each block computes
// h[m] = err_b,d . w1[:,m] for its 64 m's x all 32 d via MFMA, applies gelu
// and the w2 contraction, and writes a 32-float partial logit per (b,slice).
// ---------------------------------------------------------------------------
__global__ __launch_bounds__(256) void gate_kernel(
    const unsigned short* __restrict__ errb, const unsigned short* __restrict__ w1t,
    const float* __restrict__ b1, const float* __restrict__ w2,
    float* __restrict__ gatep) {
  __shared__ float part[4][32];
  int orig = blockIdx.x;
  int xcd = orig & 7, idx = orig >> 3;         // idx 0..31
  int b = (xcd << 2) | (idx >> 3);
  int s = idx & 7;                             // m-slice
  int tid = threadIdx.x, lane = tid & 63, wv = tid >> 6;
  int m16 = lane & 15, quad = lane >> 4;
  int mw = s * 64 + wv * 16;                   // this wave's 16 m's
  int r0 = b * 32;

  float b1v = b1[mw + m16];
  float2 w2p = ((const float2*)w2)[mw + m16];
  float w2d = w2p.x - w2p.y;

  f4 acc[2];
  acc[0] = (f4){0.f, 0.f, 0.f, 0.f};
  acc[1] = (f4){0.f, 0.f, 0.f, 0.f};

  const unsigned short* ea = errb + (size_t)(r0 + m16) * DM + quad * 8;
  const unsigned short* eb = ea + 16 * DM;
  const unsigned short* wb = w1t + (size_t)(mw + m16) * DM + quad * 8;

  #pragma unroll
  for (int ks = 0; ks < DM; ks += 32) {
    U16x8 ua0, ua1, ub;
    ua0.u = *(const uint4*)(ea + ks);
    ua1.u = *(const uint4*)(eb + ks);
    ub.u  = *(const uint4*)(wb + ks);
    acc[0] = __builtin_amdgcn_mfma_f32_16x16x32_bf16(ua0.h, ub.h, acc[0], 0, 0, 0);
    acc[1] = __builtin_amdgcn_mfma_f32_16x16x32_bf16(ua1.h, ub.h, acc[1], 0, 0, 0);
  }

  float rsum[2][4];
  #pragma unroll
  for (int rt = 0; rt < 2; ++rt) {
    #pragma unroll
    for (int r = 0; r < 4; ++r) {
      float h = acc[rt][r] + b1v;
      float gg = 0.5f * h * (1.0f + erff(h * 0.70710678f));
      rsum[rt][r] = gg * w2d;
    }
  }
  #pragma unroll
  for (int rt = 0; rt < 2; ++rt) {
    #pragma unroll
    for (int r = 0; r < 4; ++r) {
      rsum[rt][r] += __shfl_xor(rsum[rt][r], 1);
      rsum[rt][r] += __shfl_xor(rsum[rt][r], 2);
      rsum[rt][r] += __shfl_xor(rsum[rt][r], 4);
      rsum[rt][r] += __shfl_xor(rsum[rt][r], 8);
    }
  }
  if (m16 == 0) {
    #pragma unroll
    for (int rt = 0; rt < 2; ++rt)
      #pragma unroll
      for (int r = 0; r < 4; ++r)
        part[wv][rt * 16 + quad * 4 + r] = rsum[rt][r];
  }
  __syncthreads();

  if (tid < 32) {
    float p = part[0][tid] + part[1][tid] + part[2][tid] + part[3][tid];
    gatep[(size_t)(((b << 3) | s) << 5) | tid] = p;   // partial for (b, d=tid)
  }
}

// ---------------------------------------------------------------------------
// K3 tail: 256 blocks = (b, o-eighth of 24). Pure elementwise: sum the 8
// gate partials, bn constants from bnp, gated fusion, coalesced out writes.
// ---------------------------------------------------------------------------
__global__ __launch_bounds__(256) void tail_kernel(
    const float* __restrict__ gatep, const float* __restrict__ b2,
    const float* __restrict__ V, const float* __restrict__ ymean,
    const float* __restrict__ bnp,
    const float* __restrict__ gamma, const float* __restrict__ beta,
    float* __restrict__ out) {
  __shared__ float vsh[32 * 28], ysh[32 * 28];
  __shared__ float gsh[32], ssh[32], osh[32];
  int g = blockIdx.x, tid = threadIdx.x;
  int xcd = g & 7, idx = g >> 3;
  int b = (xcd << 2) | (idx >> 3);
  int o0 = (idx & 7) * 24;

  if (tid < 192) {
    int dd = tid / 6, c4 = tid % 6;
    size_t goff = (size_t)(b * DD + dd) * OO + o0;
    float4 v = ((const float4*)(V + goff))[c4];
    float4 y = ((const float4*)(ymean + goff))[c4];
    *(float4*)&vsh[dd * 28 + c4 * 4] = v;
    *(float4*)&ysh[dd * 28 + c4 * 4] = y;
  }

  if (tid < 32) {
    float ld = b2[0] - b2[1];
    #pragma unroll
    for (int s = 0; s < 8; ++s)
      ld += gatep[(size_t)(((b << 3) | s) << 5) | tid];
    gsh[tid] = 1.0f / (1.0f + expf(-ld));      // gate w0 for (b, d=tid)
    float S = 0.f, S2 = 0.f;
    const float* pd = bnp + (tid << 5);
    #pragma unroll 8
    for (int bb = 0; bb < 32; ++bb) { S += pd[bb]; S2 += pd[1024 + bb]; }
    const float inv = 1.0f / (BB * OO);
    float mu = S * inv;
    float var = S2 * inv - mu * mu;
    float gg = gamma[tid] * rsqrtf(var + 1e-5f);
    ssh[tid] = gg;
    osh[tid] = beta[tid] - mu * gg;
  }
  __syncthreads();

  if (tid < 192) {
    int op = tid >> 3, c4 = tid & 7;
    float4 r;
    #pragma unroll
    for (int j = 0; j < 4; ++j) {
      int dd = c4 * 4 + j;
      float v  = vsh[dd * 28 + op];
      float ym = ysh[dd * 28 + op];
      float gg = gsh[dd];
      float y  = v * ssh[dd] + osh[dd];
      ((float*)&r)[j] = ym * gg + y * (1.0f - gg);
    }
    ((float4*)(out + (size_t)(b * OO + o0 + op) * DD))[c4] = r;
  }
}

// ---------------------------------------------------------------------------
extern "C" void kernel_launch(void* const* d_in, const int* in_sizes, int n_in,
                              void* d_out, int out_size, void* d_ws, size_t ws_size,
                              hipStream_t stream) {
  const float* x      = (const float*)d_in[0];
  const float* x_date = (const float*)d_in[1];
  const float* y_date = (const float*)d_in[2];
  const float* w1     = (const float*)d_in[3];
  const float* b1     = (const float*)d_in[4];
  const float* w2     = (const float*)d_in[5];
  const float* b2     = (const float*)d_in[6];
  const float* gamma  = (const float*)d_in[7];
  const float* beta   = (const float*)d_in[8];
  float* out = (float*)d_out;

  float* ws    = (float*)d_ws;
  float* V     = ws;                             // [0, 196608)   (B,D,O)
  float* ymean = ws + 196608;                    // [196608, 393216)
  float* bnp   = ws + 393216;                    // [393216, 395264)
  unsigned short* errb = (unsigned short*)(ws + 395264);   // [395264, 657408) 1024x512 bf16
  unsigned short* w1t  = (unsigned short*)(ws + 657408);   // [657408, 788480) 512x512 bf16 (m,l)
  float* gatep = ws + 788480;                    // [788480, 796672) 32b x 8s x 32d

  fused_kernel<<<1088, 512, 0, stream>>>(x, x_date, y_date, w1,
                                         V, ymean, bnp, errb, w1t);
  gate_kernel<<<256, 256, 0, stream>>>(errb, w1t, b1, w2, gatep);
  tail_kernel<<<256, 256, 0, stream>>>(gatep, b2, V, ymean, bnp,
                                       gamma, beta, out);
}

// Round 14
// 123.737 us; speedup vs baseline: 1.3868x; 1.0808x over previous
//
#include <hip/hip_runtime.h>
#include <math.h>

#define BB 32
#define LL 512
#define DD 32
#define KK 6
#define OO 192
#define DM 512

typedef __fp16 h2 __attribute__((ext_vector_type(2)));
typedef __fp16 h8 __attribute__((ext_vector_type(8)));
union F2H { float f; h2 h; };
__device__ __forceinline__ float asF(h2 h) { F2H u; u.h = h; return u.f; }
__device__ __forceinline__ h2 asH(float f) { F2H u; u.f = f; return u.h; }

typedef short bf16x8 __attribute__((ext_vector_type(8)));
typedef float f4 __attribute__((ext_vector_type(4)));
union U16x8 { uint4 u; bf16x8 h; };
union UH8F { uint4 u; h8 h; };

__device__ __forceinline__ unsigned short f2bf(float x) {   // RNE f32->bf16
  unsigned int u = __float_as_uint(x);
  u = (u + 0x7FFF + ((u >> 16) & 1)) >> 16;
  return (unsigned short)u;
}

// bare HW 2^x via the COMPILER-KNOWN intrinsic (hazards handled by the
// backend — R13's inline-asm v_exp_f32 NaN'd because the hazard recognizer
// treats asm as opaque and skipped the required wait-states).
__device__ __forceinline__ float exp2_hw(float x) {
  return __builtin_amdgcn_exp2f(x);
}

#define MOVDPP(x, ctrl) \
  __int_as_float(__builtin_amdgcn_mov_dpp(__float_as_int(x), ctrl, 0xf, 0xf, true))

// LDS layout (float slots), per-(b,d) blocks, COLUMN-MAJOR storage.
// CSTR2=524: 16B-aligned columns (sort gather = conflict-free b128).
#define CSTR2 524
#define XD0   0                  // 6 cols x 524            (3144)
#define XV0   3144               // 1 col x 524             (524) -> 3668
#define MEDO  3668               // 7
#define STDO  3675               // 7
#define SAO   3682               // 6
#define SCO   3688               // 6
#define BNR   3694               // 16 -> 3710
// overlays of the dead XD region after the map phase:
#define XMP   0                  // Xm pack: [512 l][8 f16] = 2048 floats
#define YMP   2048               // Ym pack: [192 o][8 f16] = 768 -> 2816 < 3144
#define DEN   3712               // [8 wv][96]  (768)
#define NUM   4480               // [8 wv][96]  (768)
#define LDSF  5248               // 21.0 KB -> 4 blocks/CU

// ---------------------------------------------------------------------------
// In-register bitonic sort of 512 floats across one wave (8 elems/lane).
// ---------------------------------------------------------------------------
__device__ __forceinline__ void sort512(float v[8], int lane) {
  #pragma unroll
  for (int k = 2; k <= 512; k <<= 1) {
    #pragma unroll
    for (int j = k >> 1; j > 0; j >>= 1) {
      if (j >= 8) {
        int jj = j >> 3;
        bool lower = (lane & jj) == 0;
        bool asc = ((lane << 3) & k) == 0;
        bool keepmin = (asc == lower);
        #pragma unroll
        for (int r = 0; r < 8; ++r) {
          float o;
          if (jj == 1)      o = MOVDPP(v[r], 0xB1);   // quad_perm [1,0,3,2]
          else if (jj == 2) o = MOVDPP(v[r], 0x4E);   // quad_perm [2,3,0,1]
          else if (jj == 8) o = MOVDPP(v[r], 0x128);  // row_ror:8 == xor8
          else              o = __shfl_xor(v[r], jj);
          v[r] = keepmin ? fminf(v[r], o) : fmaxf(v[r], o);
        }
      } else {
        #pragma unroll
        for (int r = 0; r < 8; ++r) {
          if ((r & j) == 0) {
            int r2 = r | j;
            bool asc = (((lane << 3) | r) & k) == 0;
            float a = v[r], b = v[r2];
            float lo = fminf(a, b), hi = fmaxf(a, b);
            v[r]  = asc ? lo : hi;
            v[r2] = asc ? hi : lo;
          }
        }
      }
    }
  }
}

// ---------------------------------------------------------------------------
// K1 fused: blocks 0..1023 = (b, d), 512 threads, 4 blocks/CU x 8 waves.
// One sort per wave (7 sorts, 1 round). Attention: wave = (o-half,
// l-quarter), MFMA f16, bare v_exp_f32 via builtin, LDS den/num combine.
// Blocks 1024..1087: w1 -> w1t bf16.
// ---------------------------------------------------------------------------
__global__ __launch_bounds__(512, 8) void fused_kernel(
    const float* __restrict__ x, const float* __restrict__ x_date,
    const float* __restrict__ y_date, const float* __restrict__ w1,
    float* __restrict__ V, float* __restrict__ ymean,
    float* __restrict__ bnp, unsigned short* __restrict__ errb,
    unsigned short* __restrict__ w1t) {
  __shared__ float lds[LDSF];
  int orig = blockIdx.x;
  int tid = threadIdx.x, lane = tid & 63, wv = tid >> 6;

  if (orig >= 1024) {
    // ---- w1 -> w1t bf16, 64x64 tile (independent of main path) ----
    float* tw = lds;                           // 64*68 = 4352 floats, fits
    int id = orig - 1024;                      // 0..63
    int l0 = (id & 7) * 64, m0 = (id >> 3) * 64;
    #pragma unroll
    for (int it = 0; it < 2; ++it) {           // 64 l-rows x 16 float4
      int f = tid + it * 512;
      int row = f >> 4, c4 = f & 15;
      float4 v = ((const float4*)(w1 + (size_t)(l0 + row) * DM + m0))[c4];
      float* p = &tw[row * 68 + c4 * 4];
      p[0] = v.x; p[1] = v.y; p[2] = v.z; p[3] = v.w;
    }
    __syncthreads();
    unsigned int* w1t32 = (unsigned int*)w1t;
    #pragma unroll
    for (int it = 0; it < 4; ++it) {           // 64 m-rows x 32 uints
      int f = tid + it * 512;
      int mr = f >> 5, c = f & 31;
      float a = tw[(c * 2 + 0) * 68 + mr];
      float b = tw[(c * 2 + 1) * 68 + mr];
      unsigned int u = (unsigned int)f2bf(a) | ((unsigned int)f2bf(b) << 16);
      w1t32[(size_t)(m0 + mr) * (DM / 2) + (l0 >> 1) + c] = u;
    }
    return;
  }

  // XCD-aware swizzle: 128 blocks per XCD = 4 b's x 32 d's.
  int xcd = orig & 7, idx = orig >> 3;         // idx 0..127
  int b = (xcd << 2) | (idx >> 5);
  int d = idx & 31;
  int lbid = (b << 5) | d;

  // ---- staging: x_date rows (3 float2, 24B contiguous) + x (1 float) ----
  const float* xs = x_date + (size_t)b * LL * 192 + d * 6;
  #pragma unroll
  for (int it = 0; it < 3; ++it) {             // 512 rows x 3 float2
    int f = tid + it * 512;
    int row = f / 3, c = f % 3;
    float2 v = ((const float2*)(xs + (size_t)row * 192))[c];
    lds[XD0 + (2 * c + 0) * CSTR2 + row] = v.x;
    lds[XD0 + (2 * c + 1) * CSTR2 + row] = v.y;
  }
  lds[XV0 + tid] = x[(size_t)(b * LL + tid) * DD + d];

  // ---- prefetch y_date: waves 0..2, o = wv*64 + lane ----
  float2 yr0, yr1, yr2;
  if (wv < 3) {
    int o = wv * 64 + lane;
    const float2* yp = (const float2*)(
        y_date + (((size_t)b * OO + o) * DD + d) * KK);
    yr0 = yp[0]; yr1 = yp[1]; yr2 = yp[2];
  }
  __syncthreads();

  // ---- 7 sorts: one per wave (wv<7).  s<6: x_date col, s=6: x col ----
  if (wv < 7) {
    const float4* colp = (wv < 6)
        ? (const float4*)&lds[XD0 + wv * CSTR2 + lane * 8]
        : (const float4*)&lds[XV0 + lane * 8];
    float v[8];
    float4 c0 = colp[0], c1 = colp[1];
    v[0]=c0.x; v[1]=c0.y; v[2]=c0.z; v[3]=c0.w;
    v[4]=c1.x; v[5]=c1.y; v[6]=c1.z; v[7]=c1.w;
    sort512(v, lane);
    float e127 = __shfl(v[7], 15);
    float e128 = __shfl(v[0], 16);
    float e255 = __shfl(v[7], 31);
    float e383 = __shfl(v[7], 47);
    float e384 = __shfl(v[0], 48);
    if (lane == 0) {
      float q25 = e127 + 0.75f * (e128 - e127);   // 0.25*(n-1)=127.75
      float q75 = e383 + 0.25f * (e384 - e383);   // 0.75*(n-1)=383.25
      lds[MEDO + wv] = e255;                      // torch lower-median
      lds[STDO + wv] = q75 - q25 + 1e-6f;
    }
  }
  __syncthreads();

  if (tid < 6) {
    float a = lds[STDO + 6] / lds[STDO + tid];
    lds[SAO + tid] = a;
    lds[SCO + tid] = lds[MEDO + 6] - lds[MEDO + tid] * a;
  }
  __syncthreads();

  const float PSC = 0.58912435f;   // (1/sqrt(6)) * log2(e)

  // ---- affine map + err (bf16 to global) + packed Xm row in regs ----
  float4 packed;
  {
    int l = tid;
    float m0 = lds[SAO+0] * lds[XD0 + 0 * CSTR2 + l] + lds[SCO+0];
    float m1 = lds[SAO+1] * lds[XD0 + 1 * CSTR2 + l] + lds[SCO+1];
    float m2 = lds[SAO+2] * lds[XD0 + 2 * CSTR2 + l] + lds[SCO+2];
    float m3 = lds[SAO+3] * lds[XD0 + 3 * CSTR2 + l] + lds[SCO+3];
    float m4 = lds[SAO+4] * lds[XD0 + 4 * CSTR2 + l] + lds[SCO+4];
    float m5 = lds[SAO+5] * lds[XD0 + 5 * CSTR2 + l] + lds[SCO+5];
    float xvv = lds[XV0 + l];
    errb[(size_t)lbid * LL + l] =
        f2bf(xvv - (m0 + m1 + m2 + m3 + m4 + m5) * (1.0f / 6.0f));
    packed.x = asF(__builtin_amdgcn_cvt_pkrtz(m0 * PSC, m1 * PSC));
    packed.y = asF(__builtin_amdgcn_cvt_pkrtz(m2 * PSC, m3 * PSC));
    packed.z = asF(__builtin_amdgcn_cvt_pkrtz(m4 * PSC, m5 * PSC));
    packed.w = 0.0f;                            // k=6..7 zero pad
  }
  __syncthreads();   // all XD reads done; safe to overlay with XMP/YMP

  *(float4*)&lds[XMP + tid * 4] = packed;
  if (wv < 3) {
    int o = wv * 64 + lane;
    float q0 = lds[SAO+0] * yr0.x + lds[SCO+0];
    float q1 = lds[SAO+1] * yr0.y + lds[SCO+1];
    float q2 = lds[SAO+2] * yr1.x + lds[SCO+2];
    float q3 = lds[SAO+3] * yr1.y + lds[SCO+3];
    float q4 = lds[SAO+4] * yr2.x + lds[SCO+4];
    float q5 = lds[SAO+5] * yr2.y + lds[SCO+5];
    ymean[(size_t)lbid * OO + o] =
        (q0 + q1 + q2 + q3 + q4 + q5) * (1.0f / 6.0f);
    float4 yq;
    yq.x = asF(__builtin_amdgcn_cvt_pkrtz(q0, q1));
    yq.y = asF(__builtin_amdgcn_cvt_pkrtz(q2, q3));
    yq.z = asF(__builtin_amdgcn_cvt_pkrtz(q4, q5));
    yq.w = 0.0f;
    *(float4*)&lds[YMP + o * 4] = yq;
  }
  __syncthreads();

  // ---- attention via MFMA: wave = (o-half, l-quarter). 6 ot x 8 lt ----
  {
    int oh = wv >> 2, lq = wv & 3;
    int l15 = lane & 15, kg = lane >> 4;
    uint4 zero4 = make_uint4(0u, 0u, 0u, 0u);

    UH8F bf[6];
    #pragma unroll
    for (int ot = 0; ot < 6; ++ot) {
      int brow = (oh * 6 + ot) * 16 + l15;
      uint4 bu = *(const uint4*)&lds[YMP + brow * 4];
      bf[ot].u = (kg == 0) ? bu : zero4;       // k>=8 lanes feed zeros
    }

    float den[6] = {0.f,0.f,0.f,0.f,0.f,0.f};
    float num[6] = {0.f,0.f,0.f,0.f,0.f,0.f};

    for (int t = 0; t < 8; ++t) {
      int lt = lq * 8 + t;
      UH8F af;
      uint4 au = *(const uint4*)&lds[XMP + (lt * 16 + l15) * 4];
      af.u = (kg == 0) ? au : zero4;
      int rbase = lt * 16 + kg * 4;
      float4 xv4 = *(const float4*)&lds[XV0 + rbase];   // 16B-aligned
      #pragma unroll
      for (int ot = 0; ot < 6; ++ot) {
        f4 c = __builtin_amdgcn_mfma_f32_16x16x32_f16(
            af.h, bf[ot].h, (f4){0.f, 0.f, 0.f, 0.f}, 0, 0, 0);
        float e0 = exp2_hw(c[0]), e1 = exp2_hw(c[1]);
        float e2 = exp2_hw(c[2]), e3 = exp2_hw(c[3]);
        den[ot] += (e0 + e1) + (e2 + e3);
        num[ot] += (e0 * xv4.x + e1 * xv4.y) + (e2 * xv4.z + e3 * xv4.w);
      }
    }

    // reduce across the 4 k-groups (rows) -> column sums for this l-quarter
    #pragma unroll
    for (int ot = 0; ot < 6; ++ot) {
      den[ot] += __shfl_xor(den[ot], 16);
      den[ot] += __shfl_xor(den[ot], 32);
      num[ot] += __shfl_xor(num[ot], 16);
      num[ot] += __shfl_xor(num[ot], 32);
    }
    if (lane < 16) {
      #pragma unroll
      for (int ot = 0; ot < 6; ++ot) {
        lds[DEN + wv * 96 + ot * 16 + lane] = den[ot];
        lds[NUM + wv * 96 + ot * 16 + lane] = num[ot];
      }
    }
  }
  __syncthreads();

  // ---- combine l-quarters, V write, bn partials ----
  float s1 = 0.f, s2 = 0.f;
  if (tid < OO) {
    int o = tid;
    int oh2 = o / 96, r96 = o % 96;            // r96 == ot*16 + l16
    int w0 = oh2 * 4;
    float dsum = lds[DEN + (w0 + 0) * 96 + r96] + lds[DEN + (w0 + 1) * 96 + r96]
               + lds[DEN + (w0 + 2) * 96 + r96] + lds[DEN + (w0 + 3) * 96 + r96];
    float nsum = lds[NUM + (w0 + 0) * 96 + r96] + lds[NUM + (w0 + 1) * 96 + r96]
               + lds[NUM + (w0 + 2) * 96 + r96] + lds[NUM + (w0 + 3) * 96 + r96];
    float vv = nsum / dsum;
    V[(size_t)lbid * OO + o] = vv;
    s1 = vv; s2 = vv * vv;
  }
  #pragma unroll
  for (int off = 32; off > 0; off >>= 1) {
    s1 += __shfl_down(s1, off);
    s2 += __shfl_down(s2, off);
  }
  if (lane == 0) { lds[BNR + wv] = s1; lds[BNR + 8 + wv] = s2; }
  __syncthreads();
  if (tid == 0) {
    float S  = lds[BNR + 0] + lds[BNR + 1] + lds[BNR + 2];
    float S2 = lds[BNR + 8] + lds[BNR + 9] + lds[BNR + 10];
    bnp[(d << 5) | b]          = S;            // no atomics: per-(d,b)
    bnp[1024 + ((d << 5) | b)] = S2;
  }
}

// ---------------------------------------------------------------------------
// K2 gate: 256 blocks = (b, m-slice of 64). NO redundancy: each block computes
// h[m] = err_b,d . w1[:,m] for its 64 m's x all 32 d via MFMA, applies gelu
// and the w2 contraction, and writes a 32-float partial logit per (b,slice).
// ---------------------------------------------------------------------------
__global__ __launch_bounds__(256) void gate_kernel(
    const unsigned short* __restrict__ errb, const unsigned short* __restrict__ w1t,
    const float* __restrict__ b1, const float* __restrict__ w2,
    float* __restrict__ gatep) {
  __shared__ float part[4][32];
  int orig = blockIdx.x;
  int xcd = orig & 7, idx = orig >> 3;         // idx 0..31
  int b = (xcd << 2) | (idx >> 3);
  int s = idx & 7;                             // m-slice
  int tid = threadIdx.x, lane = tid & 63, wv = tid >> 6;
  int m16 = lane & 15, quad = lane >> 4;
  int mw = s * 64 + wv * 16;                   // this wave's 16 m's
  int r0 = b * 32;

  float b1v = b1[mw + m16];
  float2 w2p = ((const float2*)w2)[mw + m16];
  float w2d = w2p.x - w2p.y;

  f4 acc[2];
  acc[0] = (f4){0.f, 0.f, 0.f, 0.f};
  acc[1] = (f4){0.f, 0.f, 0.f, 0.f};

  const unsigned short* ea = errb + (size_t)(r0 + m16) * DM + quad * 8;
  const unsigned short* eb = ea + 16 * DM;
  const unsigned short* wb = w1t + (size_t)(mw + m16) * DM + quad * 8;

  #pragma unroll
  for (int ks = 0; ks < DM; ks += 32) {
    U16x8 ua0, ua1, ub;
    ua0.u = *(const uint4*)(ea + ks);
    ua1.u = *(const uint4*)(eb + ks);
    ub.u  = *(const uint4*)(wb + ks);
    acc[0] = __builtin_amdgcn_mfma_f32_16x16x32_bf16(ua0.h, ub.h, acc[0], 0, 0, 0);
    acc[1] = __builtin_amdgcn_mfma_f32_16x16x32_bf16(ua1.h, ub.h, acc[1], 0, 0, 0);
  }

  float rsum[2][4];
  #pragma unroll
  for (int rt = 0; rt < 2; ++rt) {
    #pragma unroll
    for (int r = 0; r < 4; ++r) {
      float h = acc[rt][r] + b1v;
      float gg = 0.5f * h * (1.0f + erff(h * 0.70710678f));
      rsum[rt][r] = gg * w2d;
    }
  }
  #pragma unroll
  for (int rt = 0; rt < 2; ++rt) {
    #pragma unroll
    for (int r = 0; r < 4; ++r) {
      rsum[rt][r] += __shfl_xor(rsum[rt][r], 1);
      rsum[rt][r] += __shfl_xor(rsum[rt][r], 2);
      rsum[rt][r] += __shfl_xor(rsum[rt][r], 4);
      rsum[rt][r] += __shfl_xor(rsum[rt][r], 8);
    }
  }
  if (m16 == 0) {
    #pragma unroll
    for (int rt = 0; rt < 2; ++rt)
      #pragma unroll
      for (int r = 0; r < 4; ++r)
        part[wv][rt * 16 + quad * 4 + r] = rsum[rt][r];
  }
  __syncthreads();

  if (tid < 32) {
    float p = part[0][tid] + part[1][tid] + part[2][tid] + part[3][tid];
    gatep[(size_t)(((b << 3) | s) << 5) | tid] = p;   // partial for (b, d=tid)
  }
}

// ---------------------------------------------------------------------------
// K3 tail: 256 blocks = (b, o-eighth of 24). Pure elementwise: sum the 8
// gate partials, bn constants from bnp, gated fusion, coalesced out writes.
// ---------------------------------------------------------------------------
__global__ __launch_bounds__(256) void tail_kernel(
    const float* __restrict__ gatep, const float* __restrict__ b2,
    const float* __restrict__ V, const float* __restrict__ ymean,
    const float* __restrict__ bnp,
    const float* __restrict__ gamma, const float* __restrict__ beta,
    float* __restrict__ out) {
  __shared__ float vsh[32 * 28], ysh[32 * 28];
  __shared__ float gsh[32], ssh[32], osh[32];
  int g = blockIdx.x, tid = threadIdx.x;
  int xcd = g & 7, idx = g >> 3;
  int b = (xcd << 2) | (idx >> 3);
  int o0 = (idx & 7) * 24;

  if (tid < 192) {
    int dd = tid / 6, c4 = tid % 6;
    size_t goff = (size_t)(b * DD + dd) * OO + o0;
    float4 v = ((const float4*)(V + goff))[c4];
    float4 y = ((const float4*)(ymean + goff))[c4];
    *(float4*)&vsh[dd * 28 + c4 * 4] = v;
    *(float4*)&ysh[dd * 28 + c4 * 4] = y;
  }

  if (tid < 32) {
    float ld = b2[0] - b2[1];
    #pragma unroll
    for (int s = 0; s < 8; ++s)
      ld += gatep[(size_t)(((b << 3) | s) << 5) | tid];
    gsh[tid] = 1.0f / (1.0f + expf(-ld));      // gate w0 for (b, d=tid)
    float S = 0.f, S2 = 0.f;
    const float* pd = bnp + (tid << 5);
    #pragma unroll 8
    for (int bb = 0; bb < 32; ++bb) { S += pd[bb]; S2 += pd[1024 + bb]; }
    const float inv = 1.0f / (BB * OO);
    float mu = S * inv;
    float var = S2 * inv - mu * mu;
    float gg = gamma[tid] * rsqrtf(var + 1e-5f);
    ssh[tid] = gg;
    osh[tid] = beta[tid] - mu * gg;
  }
  __syncthreads();

  if (tid < 192) {
    int op = tid >> 3, c4 = tid & 7;
    float4 r;
    #pragma unroll
    for (int j = 0; j < 4; ++j) {
      int dd = c4 * 4 + j;
      float v  = vsh[dd * 28 + op];
      float ym = ysh[dd * 28 + op];
      float gg = gsh[dd];
      float y  = v * ssh[dd] + osh[dd];
      ((float*)&r)[j] = ym * gg + y * (1.0f - gg);
    }
    ((float4*)(out + (size_t)(b * OO + o0 + op) * DD))[c4] = r;
  }
}

// ---------------------------------------------------------------------------
extern "C" void kernel_launch(void* const* d_in, const int* in_sizes, int n_in,
                              void* d_out, int out_size, void* d_ws, size_t ws_size,
                              hipStream_t stream) {
  const float* x      = (const float*)d_in[0];
  const float* x_date = (const float*)d_in[1];
  const float* y_date = (const float*)d_in[2];
  const float* w1     = (const float*)d_in[3];
  const float* b1     = (const float*)d_in[4];
  const float* w2     = (const float*)d_in[5];
  const float* b2     = (const float*)d_in[6];
  const float* gamma  = (const float*)d_in[7];
  const float* beta   = (const float*)d_in[8];
  float* out = (float*)d_out;

  float* ws    = (float*)d_ws;
  float* V     = ws;                             // [0, 196608)   (B,D,O)
  float* ymean = ws + 196608;                    // [196608, 393216)
  float* bnp   = ws + 393216;                    // [393216, 395264)
  unsigned short* errb = (unsigned short*)(ws + 395264);   // [395264, 657408) 1024x512 bf16
  unsigned short* w1t  = (unsigned short*)(ws + 657408);   // [657408, 788480) 512x512 bf16 (m,l)
  float* gatep = ws + 788480;                    // [788480, 796672) 32b x 8s x 32d

  fused_kernel<<<1088, 512, 0, stream>>>(x, x_date, y_date, w1,
                                         V, ymean, bnp, errb, w1t);
  gate_kernel<<<256, 256, 0, stream>>>(errb, w1t, b1, w2, gatep);
  tail_kernel<<<256, 256, 0, stream>>>(gatep, b2, V, ymean, bnp,
                                       gamma, beta, out);
}